// Round 9
// baseline (5554.781 us; speedup 1.0000x reference)
//
#include <hip/hip_runtime.h>

typedef short bf16x8 __attribute__((ext_vector_type(8)));
typedef float f32x4 __attribute__((ext_vector_type(4)));

#define AS 272   // A-matrix LDS row stride in bf16 elements (16B-aligned rows)

__device__ __forceinline__ unsigned short f2bf(float f) {
    union { float f; unsigned int u; } v; v.f = f;
    unsigned int u = v.u + 0x7FFFu + ((v.u >> 16) & 1u);
    return (unsigned short)(u >> 16);
}
__device__ __forceinline__ float bf2f(unsigned int h) {
    union { unsigned int u; float f; } v; v.u = h << 16; return v.f;
}
__device__ __forceinline__ float sigm(float x) {
    return 1.0f / (1.0f + __expf(-x));
}

struct f4s { float v[4]; };
__device__ __forceinline__ f4s ld4(const float* p) {
    float4 t = *(const float4*)p;
    f4s r; r.v[0] = t.x; r.v[1] = t.y; r.v[2] = t.z; r.v[3] = t.w; return r;
}

// ---------------- W staging: gather from original row-major fp32 W[256][256] ----------------
// Wsl fragment layout (per 32-k slice): idx = q*2048 + n*8 + j  <=>  W[kk*32+q*8+j][n]
struct wslice { uint4 v[2]; };

__device__ __forceinline__ wslice gather_slice(const float* __restrict__ w,
                                               int kk, int tid) {
    wslice s;
    const int n = tid & 255;
#pragma unroll
    for (int r = 0; r < 2; ++r) {
        const int q = r * 2 + (tid >> 8);
        unsigned short t[8];
#pragma unroll
        for (int j = 0; j < 8; ++j)
            t[j] = f2bf(w[(kk * 32 + q * 8 + j) * 256 + n]);   // coalesced across lanes (n)
        uint4 u;
        u.x = t[0] | ((unsigned)t[1] << 16);
        u.y = t[2] | ((unsigned)t[3] << 16);
        u.z = t[4] | ((unsigned)t[5] << 16);
        u.w = t[6] | ((unsigned)t[7] << 16);
        s.v[r] = u;
    }
    return s;
}
__device__ __forceinline__ void dswrite_slice(unsigned short* Wsl, int buf, int tid,
                                              const wslice& s) {
    uint4* p = (uint4*)(Wsl + buf * 8192);
    p[tid] = s.v[0];
    p[512 + tid] = s.v[1];
}

__device__ __forceinline__ void do_gemm(const float* __restrict__ w,
                                        unsigned short* Asl, unsigned short* Wsl,
                                        int tid, int raP, int vbB,
                                        f32x4 aP[8], f32x4 aT0[8], f32x4 aT1[8]) {
    wslice cur = gather_slice(w, 0, tid);
    dswrite_slice(Wsl, 0, tid, cur);
    wslice nxt = gather_slice(w, 1, tid);
    __syncthreads();
    for (int kk = 0; kk < 8; ++kk) {
        bf16x8 fP  = *(const bf16x8*)(Asl + raP + kk * 32);
        bf16x8 fT0 = *(const bf16x8*)(Asl + raP + 64 * AS + kk * 32);
        bf16x8 fT1 = *(const bf16x8*)(Asl + raP + 128 * AS + kk * 32);
        const unsigned short* wb = Wsl + (kk & 1) * 8192 + vbB;
#pragma unroll
        for (int nb = 0; nb < 8; ++nb) {
            bf16x8 bw = *(const bf16x8*)(wb + nb * 128);
            aP[nb]  = __builtin_amdgcn_mfma_f32_16x16x32_bf16(fP,  bw, aP[nb],  0, 0, 0);
            aT0[nb] = __builtin_amdgcn_mfma_f32_16x16x32_bf16(fT0, bw, aT0[nb], 0, 0, 0);
            aT1[nb] = __builtin_amdgcn_mfma_f32_16x16x32_bf16(fT1, bw, aT1[nb], 0, 0, 0);
        }
        if (kk < 7) {
            dswrite_slice(Wsl, (kk + 1) & 1, tid, nxt);     // WAR-safe: that buf's reads
            if (kk < 6) nxt = gather_slice(w, kk + 2, tid); // drained at previous barrier
        }
        __syncthreads();
    }
}

__device__ __forceinline__ void el_write(unsigned short* Asl,
                                         const f32x4* aP, const f32x4* aT0, const f32x4* aT1,
                                         const float* br, int wbE, int wbO) {
#pragma unroll
    for (int nb = 0; nb < 8; ++nb) {
        const int cbase = ((nb & 1) ? wbO : wbE) + (nb >> 1) * 32;
#pragma unroll
        for (int r = 0; r < 4; ++r) {
            const float pre = aP[nb][r] + br[nb];
            const float s = sigm(pre);
            const float h = pre * s;
            const float d = s + h - h * s;  // silu'(pre)
            Asl[cbase + r * AS]            = f2bf(h);
            Asl[cbase + r * AS + 64 * AS]  = f2bf(d * aT0[nb][r]);
            Asl[cbase + r * AS + 128 * AS] = f2bf(d * aT1[nb][r]);
        }
    }
}

// ---------------- main kernel ----------------
// One WG = 64 points of one batch, all 10 solver steps. Inputs fp32, OUTPUT FP32.
__launch_bounds__(512, 1)
__global__ void k_main(const float* __restrict__ x,
                       const float* __restrict__ ctx,
                       const float* __restrict__ w1,
                       const float* __restrict__ b1,
                       const float* __restrict__ w2,
                       const float* __restrict__ b2g,
                       const float* __restrict__ w3,
                       const float* __restrict__ b3g,
                       const float* __restrict__ w4g,
                       const float* __restrict__ b4g,
                       float* __restrict__ ldacc,
                       float* __restrict__ out) {
    __shared__ unsigned short Asl[192 * AS];   // [h;t0;t1] bf16, swizzled
    __shared__ unsigned short Wsl[2 * 8192];   // double-buffered 16KB W k-slices
    __shared__ float w1r[3][256];
    __shared__ float basel[256];
    __shared__ float ctxl[128];
    __shared__ float w40[256], w41[256];
    __shared__ float ptsl[64][2];
    __shared__ float ldl[64];
    __shared__ float b4l[2];

    const int tid = threadIdx.x;
    const int wg = blockIdx.x;
    const int b = wg >> 6;
    const int n0 = (wg & 63) << 6;

    for (int i = tid; i < 768; i += 512) w1r[i >> 8][i & 255] = w1[i];
    if (tid < 128) ctxl[tid] = ctx[b * 128 + tid];
    if (tid < 256) { w40[tid] = w4g[2 * tid]; w41[tid] = w4g[2 * tid + 1]; }
    if (tid < 128) ptsl[tid >> 1][tid & 1] = x[((b << 12) + n0 + (tid >> 1)) * 2 + (tid & 1)];
    if (tid < 64) ldl[tid] = 0.0f;
    if (tid < 2) b4l[tid] = b4g[tid];
    __syncthreads();

    // base[n] = b1[n] + sum_c ctx[b][c]*w1[3+c][n]  (once per WG)
    if (tid < 256) {
        float acc = b1[tid];
        for (int c = 0; c < 128; ++c)
            acc += ctxl[c] * w1[(3 + c) * 256 + tid];
        basel[tid] = acc;
    }

    const int lane = tid & 63, wave = tid >> 6;
    const int m = lane & 15, q = lane >> 4;
    const int tw = wave & 3;                 // M-triple index
    const int nbb = (wave >> 2) << 3;        // N-block base (0 or 8)
    const int qx = q ^ ((m >> 2) & 3);       // read-side XOR swizzle
    const int raP = (tw * 16 + m) * AS + qx * 8;
    const int mw  = m ^ ((q & 1) << 3);      // write-side swizzle pieces
    const int nbx = q >> 1;
    const int wbE = (tw * 16 + q * 4) * AS + (nbb + nbx) * 16 + mw;
    const int wbO = (tw * 16 + q * 4) * AS + (nbb + (1 ^ nbx)) * 16 + mw;
    const int vbB = q * 2048 + (nbb * 16 + m) * 8;

    float b2r[8], b3r[8];
#pragma unroll
    for (int i = 0; i < 8; ++i) {
        b2r[i] = b2g[(nbb + i) * 16 + m];
        b3r[i] = b3g[(nbb + i) * 16 + m];
    }
    __syncthreads();

    const int p4 = tid >> 3;            // point for L1/L4 phases
    const int ic = tid & 7;             // 8 threads per point
    const int px = (p4 & 12) << 1;      // col XOR for rows p4, 64+p4, 128+p4

#pragma unroll 1
    for (int st = 0; st < 10; ++st) {
        const float ti = 0.1f * (float)st;
        // ---------- layer 1 ----------
        {
            const float x0 = ptsl[p4][0], x1 = ptsl[p4][1];
#pragma unroll
            for (int g = 0; g < 8; ++g) {
                const int cb = (ic << 5) + g * 4;
                const f4s wa = ld4(&w1r[0][cb]);
                const f4s wb = ld4(&w1r[1][cb]);
                const f4s wc = ld4(&w1r[2][cb]);
                const f4s bs = ld4(&basel[cb]);
                unsigned short hh[4], t0h[4], t1h[4];
#pragma unroll
                for (int e = 0; e < 4; ++e) {
                    const float pre = x0 * wa.v[e] + x1 * wb.v[e] + ti * wc.v[e] + bs.v[e];
                    const float s = sigm(pre);
                    const float h = pre * s;
                    const float d = s + h - h * s;
                    hh[e]  = f2bf(h);
                    t0h[e] = f2bf(d * wa.v[e]);
                    t1h[e] = f2bf(d * wb.v[e]);
                }
                const int colp = cb ^ px;
                uint2 v0, v1, v2;
                v0.x = hh[0]  | ((unsigned)hh[1]  << 16); v0.y = hh[2]  | ((unsigned)hh[3]  << 16);
                v1.x = t0h[0] | ((unsigned)t0h[1] << 16); v1.y = t0h[2] | ((unsigned)t0h[3] << 16);
                v2.x = t1h[0] | ((unsigned)t1h[1] << 16); v2.y = t1h[2] | ((unsigned)t1h[3] << 16);
                *(uint2*)(Asl + p4 * AS + colp) = v0;
                *(uint2*)(Asl + (64 + p4) * AS + colp) = v1;
                *(uint2*)(Asl + (128 + p4) * AS + colp) = v2;
            }
        }
        __syncthreads();

        // ---------- layer 2 ----------
        f32x4 aP[8], aT0[8], aT1[8];
#pragma unroll
        for (int i = 0; i < 8; ++i) { aP[i] = f32x4{0.f,0.f,0.f,0.f}; aT0[i] = f32x4{0.f,0.f,0.f,0.f}; aT1[i] = f32x4{0.f,0.f,0.f,0.f}; }
        do_gemm(w2, Asl, Wsl, tid, raP, vbB, aP, aT0, aT1);
        el_write(Asl, aP, aT0, aT1, b2r, wbE, wbO);
        __syncthreads();

        // ---------- layer 3 ----------
#pragma unroll
        for (int i = 0; i < 8; ++i) { aP[i] = f32x4{0.f,0.f,0.f,0.f}; aT0[i] = f32x4{0.f,0.f,0.f,0.f}; aT1[i] = f32x4{0.f,0.f,0.f,0.f}; }
        do_gemm(w3, Asl, Wsl, tid, raP, vbB, aP, aT0, aT1);
        el_write(Asl, aP, aT0, aT1, b3r, wbE, wbO);
        __syncthreads();

        // ---------- layer 4 + update ----------
        {
            float v0 = 0.f, v1 = 0.f, j00 = 0.f, j11 = 0.f;
#pragma unroll
            for (int g = 0; g < 8; ++g) {
                const int cb = (ic << 5) + g * 4;
                const int colp = cb ^ px;
                const uint2 hv  = *(const uint2*)(Asl + p4 * AS + colp);
                const uint2 t0v = *(const uint2*)(Asl + (64 + p4) * AS + colp);
                const uint2 t1v = *(const uint2*)(Asl + (128 + p4) * AS + colp);
                const f4s wa = ld4(&w40[cb]);
                const f4s wb = ld4(&w41[cb]);
                const unsigned hu[4]  = { hv.x & 0xffffu,  hv.x >> 16,  hv.y & 0xffffu,  hv.y >> 16 };
                const unsigned t0u[4] = { t0v.x & 0xffffu, t0v.x >> 16, t0v.y & 0xffffu, t0v.y >> 16 };
                const unsigned t1u[4] = { t1v.x & 0xffffu, t1v.x >> 16, t1v.y & 0xffffu, t1v.y >> 16 };
#pragma unroll
                for (int e = 0; e < 4; ++e) {
                    const float h = bf2f(hu[e]);
                    v0  += h * wa.v[e];
                    v1  += h * wb.v[e];
                    j00 += bf2f(t0u[e]) * wa.v[e];
                    j11 += bf2f(t1u[e]) * wb.v[e];
                }
            }
#pragma unroll
            for (int o = 1; o < 8; o <<= 1) {
                v0  += __shfl_xor(v0, o);
                v1  += __shfl_xor(v1, o);
                j00 += __shfl_xor(j00, o);
                j11 += __shfl_xor(j11, o);
            }
            if (ic == 0) {
                ptsl[p4][0] += 0.1f * (v0 + b4l[0]);
                ptsl[p4][1] += 0.1f * (v1 + b4l[1]);
                ldl[p4]     += 0.1f * (j00 + j11);
            }
        }
        __syncthreads();
    }

    // ---------- epilogue: FP32 output ----------
    if (tid < 128) {
        const int p = tid >> 1, c = tid & 1;
        out[((b << 12) + n0 + p) * 2 + c] = ptsl[p][c];
    }
    if (wave == 0) {
        float v = ldl[lane];
#pragma unroll
        for (int o = 32; o > 0; o >>= 1) v += __shfl_xor(v, o);
        if (lane == 0) atomicAdd(ldacc + b, v);
    }
}

// copy 64 float accumulators -> fp32 logdet outputs
__global__ void k_fin(const float* __restrict__ ldacc, float* __restrict__ out) {
    out[524288 + threadIdx.x] = ldacc[threadIdx.x];
}

extern "C" void kernel_launch(void* const* d_in, const int* in_sizes, int n_in,
                              void* d_out, int out_size, void* d_ws, size_t ws_size,
                              hipStream_t stream) {
    const float* x   = (const float*)d_in[0];
    const float* ctx = (const float*)d_in[1];
    const float* w1  = (const float*)d_in[2];
    const float* b1  = (const float*)d_in[3];
    const float* w2  = (const float*)d_in[4];
    const float* b2  = (const float*)d_in[5];
    const float* w3  = (const float*)d_in[6];
    const float* b3  = (const float*)d_in[7];
    const float* w4  = (const float*)d_in[8];
    const float* b4  = (const float*)d_in[9];

    float* ldacc = (float*)d_ws;                 // 64 floats only
    float* out = (float*)d_out;                  // FP32 output buffer

    hipMemsetAsync(d_ws, 0, 64 * sizeof(float), stream);
    k_main<<<dim3(4096), dim3(512), 0, stream>>>(x, ctx, w1, b1, w2, b2, w3, b3, w4, b4, ldacc, out);
    k_fin<<<dim3(1), dim3(64), 0, stream>>>(ldacc, out);
}

// Round 10
// 5018.760 us; speedup vs baseline: 1.1068x; 1.1068x over previous
//
#include <hip/hip_runtime.h>

typedef short bf16x8 __attribute__((ext_vector_type(8)));
typedef float f32x4 __attribute__((ext_vector_type(4)));

#define AS 272   // A-matrix LDS row stride in bf16 elements (16B-aligned rows)

__device__ __forceinline__ unsigned short f2bf(float f) {
    union { float f; unsigned int u; } v; v.f = f;
    unsigned int u = v.u + 0x7FFFu + ((v.u >> 16) & 1u);
    return (unsigned short)(u >> 16);
}
__device__ __forceinline__ float bf2f(unsigned int h) {
    union { unsigned int u; float f; } v; v.u = h << 16; return v.f;
}
__device__ __forceinline__ float sigm(float x) {
    return 1.0f / (1.0f + __expf(-x));
}

struct f4s { float v[4]; };
__device__ __forceinline__ f4s ld4(const float* p) {
    float4 t = *(const float4*)p;
    f4s r; r.v[0] = t.x; r.v[1] = t.y; r.v[2] = t.z; r.v[3] = t.w; return r;
}

// ---------------- pre-kernels ----------------

// base[b][n] = b1[n] + sum_c ctx[b][c] * w1[3+c][n]   (once per launch)
__global__ void k_base(const float* __restrict__ ctx,
                       const float* __restrict__ w1,
                       const float* __restrict__ b1,
                       float* __restrict__ base) {
    const int b = blockIdx.x, n = threadIdx.x;
    float acc = b1[n];
    for (int c = 0; c < 128; ++c)
        acc += ctx[b * 128 + c] * w1[(3 + c) * 256 + n];
    base[b * 256 + n] = acc;
}

// reorder fp32 W[256][256] into bf16 MFMA-B fragment-linear order:
// wf[((kk*4+q)*256+n)*8+j] = bf16(W[kk*32+q*8+j][n])
__global__ void k_frag(const float* __restrict__ w,
                       unsigned short* __restrict__ wf) {
    const int t = blockIdx.x * blockDim.x + threadIdx.x;  // 0..65535
    const int j = t & 7, n = (t >> 3) & 255, q = (t >> 11) & 3, kk = t >> 13;
    wf[t] = f2bf(w[(kk * 32 + q * 8 + j) * 256 + n]);
}

// ---------------- W staging: coalesced vector loads of pre-fragmented bf16 ----------------
struct wslice { uint4 v[2]; };

__device__ __forceinline__ wslice load_slice(const unsigned short* __restrict__ wf,
                                             int kk, int tid) {
    const uint4* p = (const uint4*)(wf + kk * 8192);
    wslice s;
    s.v[0] = p[tid];
    s.v[1] = p[512 + tid];
    return s;
}
__device__ __forceinline__ void dswrite_slice(unsigned short* Wsl, int buf, int tid,
                                              const wslice& s) {
    uint4* p = (uint4*)(Wsl + buf * 8192);
    p[tid] = s.v[0];
    p[512 + tid] = s.v[1];
}

__device__ __forceinline__ void do_gemm(const unsigned short* __restrict__ wf,
                                        unsigned short* Asl, unsigned short* Wsl,
                                        int tid, int raP, int vbB,
                                        f32x4 aP[8], f32x4 aT0[8], f32x4 aT1[8]) {
    wslice cur = load_slice(wf, 0, tid);
    dswrite_slice(Wsl, 0, tid, cur);
    wslice nxt = load_slice(wf, 1, tid);
    __syncthreads();
    for (int kk = 0; kk < 8; ++kk) {
        bf16x8 fP  = *(const bf16x8*)(Asl + raP + kk * 32);
        bf16x8 fT0 = *(const bf16x8*)(Asl + raP + 64 * AS + kk * 32);
        bf16x8 fT1 = *(const bf16x8*)(Asl + raP + 128 * AS + kk * 32);
        const unsigned short* wb = Wsl + (kk & 1) * 8192 + vbB;
#pragma unroll
        for (int nb = 0; nb < 8; ++nb) {
            bf16x8 bw = *(const bf16x8*)(wb + nb * 128);
            aP[nb]  = __builtin_amdgcn_mfma_f32_16x16x32_bf16(fP,  bw, aP[nb],  0, 0, 0);
            aT0[nb] = __builtin_amdgcn_mfma_f32_16x16x32_bf16(fT0, bw, aT0[nb], 0, 0, 0);
            aT1[nb] = __builtin_amdgcn_mfma_f32_16x16x32_bf16(fT1, bw, aT1[nb], 0, 0, 0);
        }
        if (kk < 7) {
            dswrite_slice(Wsl, (kk + 1) & 1, tid, nxt);     // WAR-safe: that buf's reads
            if (kk < 6) nxt = load_slice(wf, kk + 2, tid);  // drained at previous barrier
        }
        __syncthreads();
    }
}

__device__ __forceinline__ void el_write(unsigned short* Asl,
                                         const f32x4* aP, const f32x4* aT0, const f32x4* aT1,
                                         const float* br, int wbE, int wbO) {
#pragma unroll
    for (int nb = 0; nb < 8; ++nb) {
        const int cbase = ((nb & 1) ? wbO : wbE) + (nb >> 1) * 32;
#pragma unroll
        for (int r = 0; r < 4; ++r) {
            const float pre = aP[nb][r] + br[nb];
            const float s = sigm(pre);
            const float h = pre * s;
            const float d = s + h - h * s;  // silu'(pre)
            Asl[cbase + r * AS]            = f2bf(h);
            Asl[cbase + r * AS + 64 * AS]  = f2bf(d * aT0[nb][r]);
            Asl[cbase + r * AS + 128 * AS] = f2bf(d * aT1[nb][r]);
        }
    }
}

// ---------------- main kernel ----------------
// One WG = 64 points of one batch, all 10 solver steps. Inputs fp32, OUTPUT FP32.
__launch_bounds__(512, 1)
__global__ void k_main(const float* __restrict__ x,
                       const float* __restrict__ w1,
                       const float* __restrict__ b2g,
                       const float* __restrict__ b3g,
                       const float* __restrict__ w4g,
                       const float* __restrict__ b4g,
                       const unsigned short* __restrict__ w2f,
                       const unsigned short* __restrict__ w3f,
                       const float* __restrict__ basep,
                       float* __restrict__ ldacc,
                       float* __restrict__ out) {
    __shared__ unsigned short Asl[192 * AS];   // [h;t0;t1] bf16, swizzled
    __shared__ unsigned short Wsl[2 * 8192];   // double-buffered 16KB W k-slices
    __shared__ float w1r[3][256];
    __shared__ float basel[256];
    __shared__ float w40[256], w41[256];
    __shared__ float ptsl[64][2];
    __shared__ float ldl[64];
    __shared__ float b4l[2];

    const int tid = threadIdx.x;
    const int wg = blockIdx.x;
    const int b = wg >> 6;
    const int n0 = (wg & 63) << 6;

    for (int i = tid; i < 768; i += 512) w1r[i >> 8][i & 255] = w1[i];
    if (tid < 256) basel[tid] = basep[b * 256 + tid];
    if (tid < 256) { w40[tid] = w4g[2 * tid]; w41[tid] = w4g[2 * tid + 1]; }
    if (tid < 128) ptsl[tid >> 1][tid & 1] = x[((b << 12) + n0 + (tid >> 1)) * 2 + (tid & 1)];
    if (tid < 64) ldl[tid] = 0.0f;
    if (tid < 2) b4l[tid] = b4g[tid];

    const int lane = tid & 63, wave = tid >> 6;
    const int m = lane & 15, q = lane >> 4;
    const int tw = wave & 3;                 // M-triple index
    const int nbb = (wave >> 2) << 3;        // N-block base (0 or 8)
    const int qx = q ^ ((m >> 2) & 3);       // read-side XOR swizzle
    const int raP = (tw * 16 + m) * AS + qx * 8;
    const int mw  = m ^ ((q & 1) << 3);      // write-side swizzle pieces
    const int nbx = q >> 1;
    const int wbE = (tw * 16 + q * 4) * AS + (nbb + nbx) * 16 + mw;
    const int wbO = (tw * 16 + q * 4) * AS + (nbb + (1 ^ nbx)) * 16 + mw;
    const int vbB = q * 2048 + (nbb * 16 + m) * 8;

    float b2r[8], b3r[8];
#pragma unroll
    for (int i = 0; i < 8; ++i) {
        b2r[i] = b2g[(nbb + i) * 16 + m];
        b3r[i] = b3g[(nbb + i) * 16 + m];
    }
    __syncthreads();

    const int p4 = tid >> 3;            // point for L1/L4 phases
    const int ic = tid & 7;             // 8 threads per point
    const int px = (p4 & 12) << 1;      // col XOR for rows p4, 64+p4, 128+p4

#pragma unroll 1
    for (int st = 0; st < 10; ++st) {
        const float ti = 0.1f * (float)st;
        // ---------- layer 1 ----------
        {
            const float x0 = ptsl[p4][0], x1 = ptsl[p4][1];
#pragma unroll
            for (int g = 0; g < 8; ++g) {
                const int cb = (ic << 5) + g * 4;
                const f4s wa = ld4(&w1r[0][cb]);
                const f4s wb = ld4(&w1r[1][cb]);
                const f4s wc = ld4(&w1r[2][cb]);
                const f4s bs = ld4(&basel[cb]);
                unsigned short hh[4], t0h[4], t1h[4];
#pragma unroll
                for (int e = 0; e < 4; ++e) {
                    const float pre = x0 * wa.v[e] + x1 * wb.v[e] + ti * wc.v[e] + bs.v[e];
                    const float s = sigm(pre);
                    const float h = pre * s;
                    const float d = s + h - h * s;
                    hh[e]  = f2bf(h);
                    t0h[e] = f2bf(d * wa.v[e]);
                    t1h[e] = f2bf(d * wb.v[e]);
                }
                const int colp = cb ^ px;
                uint2 v0, v1, v2;
                v0.x = hh[0]  | ((unsigned)hh[1]  << 16); v0.y = hh[2]  | ((unsigned)hh[3]  << 16);
                v1.x = t0h[0] | ((unsigned)t0h[1] << 16); v1.y = t0h[2] | ((unsigned)t0h[3] << 16);
                v2.x = t1h[0] | ((unsigned)t1h[1] << 16); v2.y = t1h[2] | ((unsigned)t1h[3] << 16);
                *(uint2*)(Asl + p4 * AS + colp) = v0;
                *(uint2*)(Asl + (64 + p4) * AS + colp) = v1;
                *(uint2*)(Asl + (128 + p4) * AS + colp) = v2;
            }
        }
        __syncthreads();

        // ---------- layer 2 ----------
        f32x4 aP[8], aT0[8], aT1[8];
#pragma unroll
        for (int i = 0; i < 8; ++i) { aP[i] = f32x4{0.f,0.f,0.f,0.f}; aT0[i] = f32x4{0.f,0.f,0.f,0.f}; aT1[i] = f32x4{0.f,0.f,0.f,0.f}; }
        do_gemm(w2f, Asl, Wsl, tid, raP, vbB, aP, aT0, aT1);
        el_write(Asl, aP, aT0, aT1, b2r, wbE, wbO);
        __syncthreads();

        // ---------- layer 3 ----------
#pragma unroll
        for (int i = 0; i < 8; ++i) { aP[i] = f32x4{0.f,0.f,0.f,0.f}; aT0[i] = f32x4{0.f,0.f,0.f,0.f}; aT1[i] = f32x4{0.f,0.f,0.f,0.f}; }
        do_gemm(w3f, Asl, Wsl, tid, raP, vbB, aP, aT0, aT1);
        el_write(Asl, aP, aT0, aT1, b3r, wbE, wbO);
        __syncthreads();

        // ---------- layer 4 + update ----------
        {
            float v0 = 0.f, v1 = 0.f, j00 = 0.f, j11 = 0.f;
#pragma unroll
            for (int g = 0; g < 8; ++g) {
                const int cb = (ic << 5) + g * 4;
                const int colp = cb ^ px;
                const uint2 hv  = *(const uint2*)(Asl + p4 * AS + colp);
                const uint2 t0v = *(const uint2*)(Asl + (64 + p4) * AS + colp);
                const uint2 t1v = *(const uint2*)(Asl + (128 + p4) * AS + colp);
                const f4s wa = ld4(&w40[cb]);
                const f4s wb = ld4(&w41[cb]);
                const unsigned hu[4]  = { hv.x & 0xffffu,  hv.x >> 16,  hv.y & 0xffffu,  hv.y >> 16 };
                const unsigned t0u[4] = { t0v.x & 0xffffu, t0v.x >> 16, t0v.y & 0xffffu, t0v.y >> 16 };
                const unsigned t1u[4] = { t1v.x & 0xffffu, t1v.x >> 16, t1v.y & 0xffffu, t1v.y >> 16 };
#pragma unroll
                for (int e = 0; e < 4; ++e) {
                    const float h = bf2f(hu[e]);
                    v0  += h * wa.v[e];
                    v1  += h * wb.v[e];
                    j00 += bf2f(t0u[e]) * wa.v[e];
                    j11 += bf2f(t1u[e]) * wb.v[e];
                }
            }
#pragma unroll
            for (int o = 1; o < 8; o <<= 1) {
                v0  += __shfl_xor(v0, o);
                v1  += __shfl_xor(v1, o);
                j00 += __shfl_xor(j00, o);
                j11 += __shfl_xor(j11, o);
            }
            if (ic == 0) {
                ptsl[p4][0] += 0.1f * (v0 + b4l[0]);
                ptsl[p4][1] += 0.1f * (v1 + b4l[1]);
                ldl[p4]     += 0.1f * (j00 + j11);
            }
        }
        __syncthreads();
    }

    // ---------- epilogue: FP32 output ----------
    if (tid < 128) {
        const int p = tid >> 1, c = tid & 1;
        out[((b << 12) + n0 + p) * 2 + c] = ptsl[p][c];
    }
    if (wave == 0) {
        float v = ldl[lane];
#pragma unroll
        for (int o = 32; o > 0; o >>= 1) v += __shfl_xor(v, o);
        if (lane == 0) atomicAdd(ldacc + b, v);
    }
}

// copy 64 float accumulators -> fp32 logdet outputs
__global__ void k_fin(const float* __restrict__ ldacc, float* __restrict__ out) {
    out[524288 + threadIdx.x] = ldacc[threadIdx.x];
}

extern "C" void kernel_launch(void* const* d_in, const int* in_sizes, int n_in,
                              void* d_out, int out_size, void* d_ws, size_t ws_size,
                              hipStream_t stream) {
    const float* x   = (const float*)d_in[0];
    const float* ctx = (const float*)d_in[1];
    const float* w1  = (const float*)d_in[2];
    const float* b1  = (const float*)d_in[3];
    const float* w2  = (const float*)d_in[4];
    const float* b2  = (const float*)d_in[5];
    const float* w3  = (const float*)d_in[6];
    const float* b3  = (const float*)d_in[7];
    const float* w4  = (const float*)d_in[8];
    const float* b4  = (const float*)d_in[9];

    // d_ws layout: [0,128K) w2f bf16 | [128K,256K) w3f bf16 | [256K,320K) base fp32 | [320K,+256) ldacc
    char* ws = (char*)d_ws;
    unsigned short* w2f = (unsigned short*)ws;
    unsigned short* w3f = (unsigned short*)(ws + 131072);
    float* basep = (float*)(ws + 262144);
    float* ldacc = (float*)(ws + 327680);
    float* out = (float*)d_out;

    hipMemsetAsync(ldacc, 0, 64 * sizeof(float), stream);
    k_base<<<dim3(64), dim3(256), 0, stream>>>(ctx, w1, b1, basep);
    k_frag<<<dim3(128), dim3(512), 0, stream>>>(w2, w2f);
    k_frag<<<dim3(128), dim3(512), 0, stream>>>(w3, w3f);
    k_main<<<dim3(4096), dim3(512), 0, stream>>>(x, w1, b2, b3, w4, b4, w2f, w3f, basep, ldacc, out);
    k_fin<<<dim3(1), dim3(64), 0, stream>>>(ldacc, out);
}

// Round 11
// 3914.769 us; speedup vs baseline: 1.4189x; 1.2820x over previous
//
#include <hip/hip_runtime.h>

typedef short bf16x8 __attribute__((ext_vector_type(8)));
typedef float f32x4 __attribute__((ext_vector_type(4)));

#define AS 272   // A-matrix LDS row stride in bf16 elements (16B-aligned rows)

__device__ __forceinline__ unsigned short f2bf(float f) {
    union { float f; unsigned int u; } v; v.f = f;
    unsigned int u = v.u + 0x7FFFu + ((v.u >> 16) & 1u);
    return (unsigned short)(u >> 16);
}
__device__ __forceinline__ float bf2f(unsigned int h) {
    union { unsigned int u; float f; } v; v.u = h << 16; return v.f;
}
__device__ __forceinline__ float sigm(float x) {
    return 1.0f / (1.0f + __expf(-x));
}

struct f4s { float v[4]; };
__device__ __forceinline__ f4s ld4(const float* p) {
    float4 t = *(const float4*)p;
    f4s r; r.v[0] = t.x; r.v[1] = t.y; r.v[2] = t.z; r.v[3] = t.w; return r;
}

// ---------------- pre-kernels ----------------

// base[b][n] = b1[n] + sum_c ctx[b][c] * w1[3+c][n]   (once per launch)
__global__ void k_base(const float* __restrict__ ctx,
                       const float* __restrict__ w1,
                       const float* __restrict__ b1,
                       float* __restrict__ base) {
    const int b = blockIdx.x, n = threadIdx.x;
    float acc = b1[n];
    for (int c = 0; c < 128; ++c)
        acc += ctx[b * 128 + c] * w1[(3 + c) * 256 + n];
    base[b * 256 + n] = acc;
}

// reorder fp32 W[256][256] into bf16 MFMA-B fragment-linear order:
// wf[((kk*4+q)*256+n)*8+j] = bf16(W[kk*32+q*8+j][n])
__global__ void k_frag(const float* __restrict__ w,
                       unsigned short* __restrict__ wf) {
    const int t = blockIdx.x * blockDim.x + threadIdx.x;  // 0..65535
    const int j = t & 7, n = (t >> 3) & 255, q = (t >> 11) & 3, kk = t >> 13;
    wf[t] = f2bf(w[(kk * 32 + q * 8 + j) * 256 + n]);
}

// ---------------- gemm: B-fragments DIRECT from global (no LDS staging, no barriers) ----------------
__device__ __forceinline__ void do_gemm_direct(const unsigned short* __restrict__ wf,
                                               const unsigned short* Asl,
                                               int raP, int vbB,
                                               f32x4 aP[8], f32x4 aT0[8], f32x4 aT1[8]) {
    const bf16x8* __restrict__ wp = (const bf16x8*)wf;
    const int base = vbB >> 3;           // bf16x8-unit index
    bf16x8 cur[8], nxt[8];
#pragma unroll
    for (int nb = 0; nb < 8; ++nb) cur[nb] = wp[base + nb * 16];
#pragma unroll 1
    for (int kk = 0; kk < 8; ++kk) {
        if (kk < 7) {
#pragma unroll
            for (int nb = 0; nb < 8; ++nb) nxt[nb] = wp[(kk + 1) * 1024 + base + nb * 16];
        }
        const bf16x8 fP  = *(const bf16x8*)(Asl + raP + kk * 32);
        const bf16x8 fT0 = *(const bf16x8*)(Asl + raP + 64 * AS + kk * 32);
        const bf16x8 fT1 = *(const bf16x8*)(Asl + raP + 128 * AS + kk * 32);
#pragma unroll
        for (int nb = 0; nb < 8; ++nb) {
            aP[nb]  = __builtin_amdgcn_mfma_f32_16x16x32_bf16(fP,  cur[nb], aP[nb],  0, 0, 0);
            aT0[nb] = __builtin_amdgcn_mfma_f32_16x16x32_bf16(fT0, cur[nb], aT0[nb], 0, 0, 0);
            aT1[nb] = __builtin_amdgcn_mfma_f32_16x16x32_bf16(fT1, cur[nb], aT1[nb], 0, 0, 0);
        }
#pragma unroll
        for (int nb = 0; nb < 8; ++nb) cur[nb] = nxt[nb];
    }
}

__device__ __forceinline__ void el_write(unsigned short* Asl,
                                         const f32x4* aP, const f32x4* aT0, const f32x4* aT1,
                                         const float* br, int wbE, int wbO) {
#pragma unroll
    for (int nb = 0; nb < 8; ++nb) {
        const int cbase = ((nb & 1) ? wbO : wbE) + (nb >> 1) * 32;
#pragma unroll
        for (int r = 0; r < 4; ++r) {
            const float pre = aP[nb][r] + br[nb];
            const float s = sigm(pre);
            const float h = pre * s;
            const float d = s + h - h * s;  // silu'(pre)
            Asl[cbase + r * AS]            = f2bf(h);
            Asl[cbase + r * AS + 64 * AS]  = f2bf(d * aT0[nb][r]);
            Asl[cbase + r * AS + 128 * AS] = f2bf(d * aT1[nb][r]);
        }
    }
}

// ---------------- main kernel ----------------
// One WG = 64 points of one batch, all 10 solver steps. Inputs fp32, OUTPUT FP32.
// 4 barriers per step (L1 / L2 / L3 / L4 boundaries) — no staging barriers.
__launch_bounds__(512, 2)
__global__ void k_main(const float* __restrict__ x,
                       const float* __restrict__ w1,
                       const float* __restrict__ b2g,
                       const float* __restrict__ b3g,
                       const float* __restrict__ w4g,
                       const float* __restrict__ b4g,
                       const unsigned short* __restrict__ w2f,
                       const unsigned short* __restrict__ w3f,
                       const float* __restrict__ basep,
                       float* __restrict__ ldacc,
                       float* __restrict__ out) {
    __shared__ unsigned short Asl[192 * AS];   // [h;t0;t1] bf16, swizzled
    __shared__ float w1r[3][256];
    __shared__ float basel[256];
    __shared__ float w40[256], w41[256];
    __shared__ float ptsl[64][2];
    __shared__ float ldl[64];
    __shared__ float b4l[2];

    const int tid = threadIdx.x;
    const int wg = blockIdx.x;
    const int b = wg >> 6;
    const int n0 = (wg & 63) << 6;

    for (int i = tid; i < 768; i += 512) w1r[i >> 8][i & 255] = w1[i];
    if (tid < 256) basel[tid] = basep[b * 256 + tid];
    if (tid < 256) { w40[tid] = w4g[2 * tid]; w41[tid] = w4g[2 * tid + 1]; }
    if (tid < 128) ptsl[tid >> 1][tid & 1] = x[((b << 12) + n0 + (tid >> 1)) * 2 + (tid & 1)];
    if (tid < 64) ldl[tid] = 0.0f;
    if (tid < 2) b4l[tid] = b4g[tid];

    const int lane = tid & 63, wave = tid >> 6;
    const int m = lane & 15, q = lane >> 4;
    const int tw = wave & 3;                 // M-triple index
    const int nbb = (wave >> 2) << 3;        // N-block base (0 or 8)
    const int qx = q ^ ((m >> 2) & 3);       // read-side XOR swizzle
    const int raP = (tw * 16 + m) * AS + qx * 8;
    const int mw  = m ^ ((q & 1) << 3);      // write-side swizzle pieces
    const int nbx = q >> 1;
    const int wbE = (tw * 16 + q * 4) * AS + (nbb + nbx) * 16 + mw;
    const int wbO = (tw * 16 + q * 4) * AS + (nbb + (1 ^ nbx)) * 16 + mw;
    const int vbB = q * 2048 + (nbb * 16 + m) * 8;

    float b2r[8], b3r[8];
#pragma unroll
    for (int i = 0; i < 8; ++i) {
        b2r[i] = b2g[(nbb + i) * 16 + m];
        b3r[i] = b3g[(nbb + i) * 16 + m];
    }
    __syncthreads();

    const int p4 = tid >> 3;            // point for L1/L4 phases
    const int ic = tid & 7;             // 8 threads per point
    const int px = (p4 & 12) << 1;      // col XOR for rows p4, 64+p4, 128+p4

#pragma unroll 1
    for (int st = 0; st < 10; ++st) {
        const float ti = 0.1f * (float)st;
        // ---------- layer 1 ----------
        {
            const float x0 = ptsl[p4][0], x1 = ptsl[p4][1];
#pragma unroll
            for (int g = 0; g < 8; ++g) {
                const int cb = (ic << 5) + g * 4;
                const f4s wa = ld4(&w1r[0][cb]);
                const f4s wb = ld4(&w1r[1][cb]);
                const f4s wc = ld4(&w1r[2][cb]);
                const f4s bs = ld4(&basel[cb]);
                unsigned short hh[4], t0h[4], t1h[4];
#pragma unroll
                for (int e = 0; e < 4; ++e) {
                    const float pre = x0 * wa.v[e] + x1 * wb.v[e] + ti * wc.v[e] + bs.v[e];
                    const float s = sigm(pre);
                    const float h = pre * s;
                    const float d = s + h - h * s;
                    hh[e]  = f2bf(h);
                    t0h[e] = f2bf(d * wa.v[e]);
                    t1h[e] = f2bf(d * wb.v[e]);
                }
                const int colp = cb ^ px;
                uint2 v0, v1, v2;
                v0.x = hh[0]  | ((unsigned)hh[1]  << 16); v0.y = hh[2]  | ((unsigned)hh[3]  << 16);
                v1.x = t0h[0] | ((unsigned)t0h[1] << 16); v1.y = t0h[2] | ((unsigned)t0h[3] << 16);
                v2.x = t1h[0] | ((unsigned)t1h[1] << 16); v2.y = t1h[2] | ((unsigned)t1h[3] << 16);
                *(uint2*)(Asl + p4 * AS + colp) = v0;
                *(uint2*)(Asl + (64 + p4) * AS + colp) = v1;
                *(uint2*)(Asl + (128 + p4) * AS + colp) = v2;
            }
        }
        __syncthreads();

        // ---------- layer 2 (barrier-free K-loop) ----------
        f32x4 aP[8], aT0[8], aT1[8];
#pragma unroll
        for (int i = 0; i < 8; ++i) { aP[i] = f32x4{0.f,0.f,0.f,0.f}; aT0[i] = f32x4{0.f,0.f,0.f,0.f}; aT1[i] = f32x4{0.f,0.f,0.f,0.f}; }
        do_gemm_direct(w2f, Asl, raP, vbB, aP, aT0, aT1);
        el_write(Asl, aP, aT0, aT1, b2r, wbE, wbO);
        __syncthreads();

        // ---------- layer 3 (barrier-free K-loop) ----------
#pragma unroll
        for (int i = 0; i < 8; ++i) { aP[i] = f32x4{0.f,0.f,0.f,0.f}; aT0[i] = f32x4{0.f,0.f,0.f,0.f}; aT1[i] = f32x4{0.f,0.f,0.f,0.f}; }
        do_gemm_direct(w3f, Asl, raP, vbB, aP, aT0, aT1);
        el_write(Asl, aP, aT0, aT1, b3r, wbE, wbO);
        __syncthreads();

        // ---------- layer 4 + update ----------
        {
            float v0 = 0.f, v1 = 0.f, j00 = 0.f, j11 = 0.f;
#pragma unroll
            for (int g = 0; g < 8; ++g) {
                const int cb = (ic << 5) + g * 4;
                const int colp = cb ^ px;
                const uint2 hv  = *(const uint2*)(Asl + p4 * AS + colp);
                const uint2 t0v = *(const uint2*)(Asl + (64 + p4) * AS + colp);
                const uint2 t1v = *(const uint2*)(Asl + (128 + p4) * AS + colp);
                const f4s wa = ld4(&w40[cb]);
                const f4s wb = ld4(&w41[cb]);
                const unsigned hu[4]  = { hv.x & 0xffffu,  hv.x >> 16,  hv.y & 0xffffu,  hv.y >> 16 };
                const unsigned t0u[4] = { t0v.x & 0xffffu, t0v.x >> 16, t0v.y & 0xffffu, t0v.y >> 16 };
                const unsigned t1u[4] = { t1v.x & 0xffffu, t1v.x >> 16, t1v.y & 0xffffu, t1v.y >> 16 };
#pragma unroll
                for (int e = 0; e < 4; ++e) {
                    const float h = bf2f(hu[e]);
                    v0  += h * wa.v[e];
                    v1  += h * wb.v[e];
                    j00 += bf2f(t0u[e]) * wa.v[e];
                    j11 += bf2f(t1u[e]) * wb.v[e];
                }
            }
#pragma unroll
            for (int o = 1; o < 8; o <<= 1) {
                v0  += __shfl_xor(v0, o);
                v1  += __shfl_xor(v1, o);
                j00 += __shfl_xor(j00, o);
                j11 += __shfl_xor(j11, o);
            }
            if (ic == 0) {
                ptsl[p4][0] += 0.1f * (v0 + b4l[0]);
                ptsl[p4][1] += 0.1f * (v1 + b4l[1]);
                ldl[p4]     += 0.1f * (j00 + j11);
            }
        }
        __syncthreads();
    }

    // ---------- epilogue: FP32 output ----------
    if (tid < 128) {
        const int p = tid >> 1, c = tid & 1;
        out[((b << 12) + n0 + p) * 2 + c] = ptsl[p][c];
    }
    if (wave == 0) {
        float v = ldl[lane];
#pragma unroll
        for (int o = 32; o > 0; o >>= 1) v += __shfl_xor(v, o);
        if (lane == 0) atomicAdd(ldacc + b, v);
    }
}

// copy 64 float accumulators -> fp32 logdet outputs
__global__ void k_fin(const float* __restrict__ ldacc, float* __restrict__ out) {
    out[524288 + threadIdx.x] = ldacc[threadIdx.x];
}

extern "C" void kernel_launch(void* const* d_in, const int* in_sizes, int n_in,
                              void* d_out, int out_size, void* d_ws, size_t ws_size,
                              hipStream_t stream) {
    const float* x   = (const float*)d_in[0];
    const float* ctx = (const float*)d_in[1];
    const float* w1  = (const float*)d_in[2];
    const float* b1  = (const float*)d_in[3];
    const float* w2  = (const float*)d_in[4];
    const float* b2  = (const float*)d_in[5];
    const float* w3  = (const float*)d_in[6];
    const float* b3  = (const float*)d_in[7];
    const float* w4  = (const float*)d_in[8];
    const float* b4  = (const float*)d_in[9];

    // d_ws layout: [0,128K) w2f bf16 | [128K,256K) w3f bf16 | [256K,320K) base fp32 | [320K,+256) ldacc
    char* ws = (char*)d_ws;
    unsigned short* w2f = (unsigned short*)ws;
    unsigned short* w3f = (unsigned short*)(ws + 131072);
    float* basep = (float*)(ws + 262144);
    float* ldacc = (float*)(ws + 327680);
    float* out = (float*)d_out;

    hipMemsetAsync(ldacc, 0, 64 * sizeof(float), stream);
    k_base<<<dim3(64), dim3(256), 0, stream>>>(ctx, w1, b1, basep);
    k_frag<<<dim3(128), dim3(512), 0, stream>>>(w2, w2f);
    k_frag<<<dim3(128), dim3(512), 0, stream>>>(w3, w3f);
    k_main<<<dim3(4096), dim3(512), 0, stream>>>(x, w1, b2, b3, w4, b4, w2f, w3f, basep, ldacc, out);
    k_fin<<<dim3(1), dim3(64), 0, stream>>>(ldacc, out);
}

// Round 12
// 3338.707 us; speedup vs baseline: 1.6638x; 1.1725x over previous
//
#include <hip/hip_runtime.h>

typedef short bf16x8 __attribute__((ext_vector_type(8)));
typedef float f32x4 __attribute__((ext_vector_type(4)));

#define AS 272   // A-matrix LDS row stride in bf16 elements (16B-aligned rows)

__device__ __forceinline__ unsigned short f2bf(float f) {      // RNE (pre-kernels only)
    union { float f; unsigned int u; } v; v.f = f;
    unsigned int u = v.u + 0x7FFFu + ((v.u >> 16) & 1u);
    return (unsigned short)(u >> 16);
}
__device__ __forceinline__ unsigned short f2bf_fast(float f) { // round-half-up, 2 ops
    union { float f; unsigned int u; } v; v.f = f;
    return (unsigned short)((v.u + 0x8000u) >> 16);
}
__device__ __forceinline__ unsigned pack2bf(float a, float b) { // [lo=a, hi=b]
    union { float f; unsigned u; } x, y; x.f = a; y.f = b;
    return ((x.u + 0x8000u) >> 16) | ((y.u + 0x8000u) & 0xffff0000u);
}
__device__ __forceinline__ float bf2f(unsigned int h) {
    union { unsigned int u; float f; } v; v.u = h << 16; return v.f;
}
__device__ __forceinline__ float sigm(float x) {
    return __builtin_amdgcn_rcpf(1.0f + __expf(-x));   // rcp: ~1 ulp, swallowed by bf16
}

struct f4s { float v[4]; };
__device__ __forceinline__ f4s ld4(const float* p) {
    float4 t = *(const float4*)p;
    f4s r; r.v[0] = t.x; r.v[1] = t.y; r.v[2] = t.z; r.v[3] = t.w; return r;
}

// ---------------- pre-kernels ----------------

__global__ void k_base(const float* __restrict__ ctx,
                       const float* __restrict__ w1,
                       const float* __restrict__ b1,
                       float* __restrict__ base) {
    const int b = blockIdx.x, n = threadIdx.x;
    float acc = b1[n];
    for (int c = 0; c < 128; ++c)
        acc += ctx[b * 128 + c] * w1[(3 + c) * 256 + n];
    base[b * 256 + n] = acc;
}

// wf[((kk*4+q)*256+n)*8+j] = bf16(W[kk*32+q*8+j][n])
__global__ void k_frag(const float* __restrict__ w,
                       unsigned short* __restrict__ wf) {
    const int t = blockIdx.x * blockDim.x + threadIdx.x;  // 0..65535
    const int j = t & 7, n = (t >> 3) & 255, q = (t >> 11) & 3, kk = t >> 13;
    wf[t] = f2bf(w[(kk * 32 + q * 8 + j) * 256 + n]);
}

// ---------------- gemm: B-fragments direct from global (no staging barriers) ----------------
__device__ __forceinline__ void do_gemm_direct(const unsigned short* __restrict__ wf,
                                               const unsigned short* Asl,
                                               int raP, int vbB,
                                               f32x4 aP[8], f32x4 aT0[8], f32x4 aT1[8]) {
    const bf16x8* __restrict__ wp = (const bf16x8*)wf;
    const int base = vbB >> 3;           // bf16x8-unit index
    bf16x8 cur[8], nxt[8];
#pragma unroll
    for (int nb = 0; nb < 8; ++nb) cur[nb] = wp[base + nb * 16];
#pragma unroll 1
    for (int kk = 0; kk < 8; ++kk) {
        if (kk < 7) {
#pragma unroll
            for (int nb = 0; nb < 8; ++nb) nxt[nb] = wp[(kk + 1) * 1024 + base + nb * 16];
        }
        const bf16x8 fP  = *(const bf16x8*)(Asl + raP + kk * 32);
        const bf16x8 fT0 = *(const bf16x8*)(Asl + raP + 64 * AS + kk * 32);
        const bf16x8 fT1 = *(const bf16x8*)(Asl + raP + 128 * AS + kk * 32);
#pragma unroll
        for (int nb = 0; nb < 8; ++nb) {
            aP[nb]  = __builtin_amdgcn_mfma_f32_16x16x32_bf16(fP,  cur[nb], aP[nb],  0, 0, 0);
            aT0[nb] = __builtin_amdgcn_mfma_f32_16x16x32_bf16(fT0, cur[nb], aT0[nb], 0, 0, 0);
            aT1[nb] = __builtin_amdgcn_mfma_f32_16x16x32_bf16(fT1, cur[nb], aT1[nb], 0, 0, 0);
        }
#pragma unroll
        for (int nb = 0; nb < 8; ++nb) cur[nb] = nxt[nb];
    }
}

__device__ __forceinline__ void el_write(unsigned short* Asl,
                                         const f32x4* aP, const f32x4* aT0, const f32x4* aT1,
                                         const float* br, int wbE, int wbO) {
#pragma unroll
    for (int nb = 0; nb < 8; ++nb) {
        const int cbase = ((nb & 1) ? wbO : wbE) + (nb >> 1) * 32;
#pragma unroll
        for (int r = 0; r < 4; ++r) {
            const float pre = aP[nb][r] + br[nb];
            const float s = sigm(pre);
            const float h = pre * s;
            const float d = s + h - h * s;  // silu'(pre)
            Asl[cbase + r * AS]            = f2bf_fast(h);
            Asl[cbase + r * AS + 64 * AS]  = f2bf_fast(d * aT0[nb][r]);
            Asl[cbase + r * AS + 128 * AS] = f2bf_fast(d * aT1[nb][r]);
        }
    }
}

// ---------------- main kernel ----------------
__launch_bounds__(512, 2)
__global__ void k_main(const float* __restrict__ x,
                       const float* __restrict__ w1,
                       const float* __restrict__ b2g,
                       const float* __restrict__ b3g,
                       const float* __restrict__ w4g,
                       const float* __restrict__ b4g,
                       const unsigned short* __restrict__ w2f,
                       const unsigned short* __restrict__ w3f,
                       const float* __restrict__ basep,
                       float* __restrict__ ldacc,
                       float* __restrict__ out) {
    __shared__ unsigned short Asl[192 * AS];   // [h;t0;t1] bf16, swizzled
    __shared__ float w1r[3][256];
    __shared__ float basel[256];
    __shared__ float w40[256], w41[256];
    __shared__ float ptsl[64][2];
    __shared__ float ldl[64];
    __shared__ float b4l[2];

    const int tid = threadIdx.x;
    const int wg = blockIdx.x;
    const int b = wg >> 6;
    const int n0 = (wg & 63) << 6;

    for (int i = tid; i < 768; i += 512) w1r[i >> 8][i & 255] = w1[i];
    if (tid < 256) basel[tid] = basep[b * 256 + tid];
    if (tid < 256) { w40[tid] = w4g[2 * tid]; w41[tid] = w4g[2 * tid + 1]; }
    if (tid < 128) ptsl[tid >> 1][tid & 1] = x[((b << 12) + n0 + (tid >> 1)) * 2 + (tid & 1)];
    if (tid < 64) ldl[tid] = 0.0f;
    if (tid < 2) b4l[tid] = b4g[tid];

    const int lane = tid & 63, wave = tid >> 6;
    const int m = lane & 15, q = lane >> 4;
    const int tw = wave & 3;                 // M-triple index
    const int nbb = (wave >> 2) << 3;        // N-block base (0 or 8)
    const int qx = q ^ ((m >> 2) & 3);       // read-side XOR swizzle
    const int raP = (tw * 16 + m) * AS + qx * 8;
    const int mw  = m ^ ((q & 1) << 3);      // write-side swizzle pieces
    const int nbx = q >> 1;
    const int wbE = (tw * 16 + q * 4) * AS + (nbb + nbx) * 16 + mw;
    const int wbO = (tw * 16 + q * 4) * AS + (nbb + (1 ^ nbx)) * 16 + mw;
    const int vbB = q * 2048 + (nbb * 16 + m) * 8;

    float b2r[8], b3r[8];
#pragma unroll
    for (int i = 0; i < 8; ++i) {
        b2r[i] = b2g[(nbb + i) * 16 + m];
        b3r[i] = b3g[(nbb + i) * 16 + m];
    }
    __syncthreads();

    const int p4 = tid >> 3;            // point for L1/L4 phases
    const int ic = tid & 7;             // 8 threads per point
    const int px = (p4 & 12) << 1;      // col XOR for rows p4, 64+p4, 128+p4

#pragma unroll 1
    for (int st = 0; st < 10; ++st) {
        const float ti = 0.1f * (float)st;
        // ---------- layer 1 ----------
        {
            const float x0 = ptsl[p4][0], x1 = ptsl[p4][1];
#pragma unroll
            for (int g = 0; g < 8; ++g) {
                const int cb = (ic << 5) + g * 4;
                const f4s wa = ld4(&w1r[0][cb]);
                const f4s wb = ld4(&w1r[1][cb]);
                const f4s wc = ld4(&w1r[2][cb]);
                const f4s bs = ld4(&basel[cb]);
                float hf[4], t0f[4], t1f[4];
#pragma unroll
                for (int e = 0; e < 4; ++e) {
                    const float pre = x0 * wa.v[e] + x1 * wb.v[e] + ti * wc.v[e] + bs.v[e];
                    const float s = sigm(pre);
                    const float h = pre * s;
                    const float d = s + h - h * s;
                    hf[e]  = h;
                    t0f[e] = d * wa.v[e];
                    t1f[e] = d * wb.v[e];
                }
                const int colp = cb ^ px;
                uint2 v0, v1, v2;
                v0.x = pack2bf(hf[0],  hf[1]);  v0.y = pack2bf(hf[2],  hf[3]);
                v1.x = pack2bf(t0f[0], t0f[1]); v1.y = pack2bf(t0f[2], t0f[3]);
                v2.x = pack2bf(t1f[0], t1f[1]); v2.y = pack2bf(t1f[2], t1f[3]);
                *(uint2*)(Asl + p4 * AS + colp) = v0;
                *(uint2*)(Asl + (64 + p4) * AS + colp) = v1;
                *(uint2*)(Asl + (128 + p4) * AS + colp) = v2;
            }
        }
        __syncthreads();

        // ---------- layer 2 (barrier-free K-loop) ----------
        f32x4 aP[8], aT0[8], aT1[8];
#pragma unroll
        for (int i = 0; i < 8; ++i) { aP[i] = f32x4{0.f,0.f,0.f,0.f}; aT0[i] = f32x4{0.f,0.f,0.f,0.f}; aT1[i] = f32x4{0.f,0.f,0.f,0.f}; }
        do_gemm_direct(w2f, Asl, raP, vbB, aP, aT0, aT1);
        el_write(Asl, aP, aT0, aT1, b2r, wbE, wbO);
        __syncthreads();

        // ---------- layer 3 (barrier-free K-loop) ----------
#pragma unroll
        for (int i = 0; i < 8; ++i) { aP[i] = f32x4{0.f,0.f,0.f,0.f}; aT0[i] = f32x4{0.f,0.f,0.f,0.f}; aT1[i] = f32x4{0.f,0.f,0.f,0.f}; }
        do_gemm_direct(w3f, Asl, raP, vbB, aP, aT0, aT1);
        el_write(Asl, aP, aT0, aT1, b3r, wbE, wbO);
        __syncthreads();

        // ---------- layer 4 + update ----------
        {
            float v0 = 0.f, v1 = 0.f, j00 = 0.f, j11 = 0.f;
#pragma unroll
            for (int g = 0; g < 8; ++g) {
                const int cb = (ic << 5) + g * 4;
                const int colp = cb ^ px;
                const uint2 hv  = *(const uint2*)(Asl + p4 * AS + colp);
                const uint2 t0v = *(const uint2*)(Asl + (64 + p4) * AS + colp);
                const uint2 t1v = *(const uint2*)(Asl + (128 + p4) * AS + colp);
                const f4s wa = ld4(&w40[cb]);
                const f4s wb = ld4(&w41[cb]);
                const unsigned hu[4]  = { hv.x & 0xffffu,  hv.x >> 16,  hv.y & 0xffffu,  hv.y >> 16 };
                const unsigned t0u[4] = { t0v.x & 0xffffu, t0v.x >> 16, t0v.y & 0xffffu, t0v.y >> 16 };
                const unsigned t1u[4] = { t1v.x & 0xffffu, t1v.x >> 16, t1v.y & 0xffffu, t1v.y >> 16 };
#pragma unroll
                for (int e = 0; e < 4; ++e) {
                    const float h = bf2f(hu[e]);
                    v0  += h * wa.v[e];
                    v1  += h * wb.v[e];
                    j00 += bf2f(t0u[e]) * wa.v[e];
                    j11 += bf2f(t1u[e]) * wb.v[e];
                }
            }
#pragma unroll
            for (int o = 1; o < 8; o <<= 1) {
                v0  += __shfl_xor(v0, o);
                v1  += __shfl_xor(v1, o);
                j00 += __shfl_xor(j00, o);
                j11 += __shfl_xor(j11, o);
            }
            if (ic == 0) {
                ptsl[p4][0] += 0.1f * (v0 + b4l[0]);
                ptsl[p4][1] += 0.1f * (v1 + b4l[1]);
                ldl[p4]     += 0.1f * (j00 + j11);
            }
        }
        __syncthreads();
    }

    // ---------- epilogue: FP32 output ----------
    if (tid < 128) {
        const int p = tid >> 1, c = tid & 1;
        out[((b << 12) + n0 + p) * 2 + c] = ptsl[p][c];
    }
    if (wave == 0) {
        float v = ldl[lane];
#pragma unroll
        for (int o = 32; o > 0; o >>= 1) v += __shfl_xor(v, o);
        if (lane == 0) atomicAdd(ldacc + b, v);
    }
}

// copy 64 float accumulators -> fp32 logdet outputs
__global__ void k_fin(const float* __restrict__ ldacc, float* __restrict__ out) {
    out[524288 + threadIdx.x] = ldacc[threadIdx.x];
}

extern "C" void kernel_launch(void* const* d_in, const int* in_sizes, int n_in,
                              void* d_out, int out_size, void* d_ws, size_t ws_size,
                              hipStream_t stream) {
    const float* x   = (const float*)d_in[0];
    const float* ctx = (const float*)d_in[1];
    const float* w1  = (const float*)d_in[2];
    const float* b1  = (const float*)d_in[3];
    const float* w2  = (const float*)d_in[4];
    const float* b2  = (const float*)d_in[5];
    const float* w3  = (const float*)d_in[6];
    const float* b3  = (const float*)d_in[7];
    const float* w4  = (const float*)d_in[8];
    const float* b4  = (const float*)d_in[9];

    // d_ws layout: [0,128K) w2f bf16 | [128K,256K) w3f bf16 | [256K,320K) base fp32 | [320K,+256) ldacc
    char* ws = (char*)d_ws;
    unsigned short* w2f = (unsigned short*)ws;
    unsigned short* w3f = (unsigned short*)(ws + 131072);
    float* basep = (float*)(ws + 262144);
    float* ldacc = (float*)(ws + 327680);
    float* out = (float*)d_out;

    hipMemsetAsync(ldacc, 0, 64 * sizeof(float), stream);
    k_base<<<dim3(64), dim3(256), 0, stream>>>(ctx, w1, b1, basep);
    k_frag<<<dim3(128), dim3(512), 0, stream>>>(w2, w2f);
    k_frag<<<dim3(128), dim3(512), 0, stream>>>(w3, w3f);
    k_main<<<dim3(4096), dim3(512), 0, stream>>>(x, w1, b2, b3, w4, b4, w2f, w3f, basep, ldacc, out);
    k_fin<<<dim3(1), dim3(64), 0, stream>>>(ldacc, out);
}

// Round 13
// 3290.548 us; speedup vs baseline: 1.6881x; 1.0146x over previous
//
#include <hip/hip_runtime.h>

typedef short bf16x8 __attribute__((ext_vector_type(8)));
typedef float f32x4 __attribute__((ext_vector_type(4)));

#define AS 272            // A-matrix LDS row stride in bf16 elements
#define T0OFF (32 * AS)   // tangent-0 row block offset (32 points/WG)
#define T1OFF (64 * AS)   // tangent-1 row block offset

__device__ __forceinline__ unsigned short f2bf(float f) {      // RNE (pre-kernels only)
    union { float f; unsigned int u; } v; v.f = f;
    unsigned int u = v.u + 0x7FFFu + ((v.u >> 16) & 1u);
    return (unsigned short)(u >> 16);
}
__device__ __forceinline__ unsigned short f2bf_fast(float f) { // round-half-up, 2 ops
    union { float f; unsigned int u; } v; v.f = f;
    return (unsigned short)((v.u + 0x8000u) >> 16);
}
__device__ __forceinline__ unsigned pack2bf(float a, float b) { // [lo=a, hi=b]
    union { float f; unsigned u; } x, y; x.f = a; y.f = b;
    return ((x.u + 0x8000u) >> 16) | ((y.u + 0x8000u) & 0xffff0000u);
}
__device__ __forceinline__ float bf2f(unsigned int h) {
    union { unsigned int u; float f; } v; v.u = h << 16; return v.f;
}
__device__ __forceinline__ float sigm(float x) {
    return __builtin_amdgcn_rcpf(1.0f + __expf(-x));
}

struct f4s { float v[4]; };
__device__ __forceinline__ f4s ld4(const float* p) {
    float4 t = *(const float4*)p;
    f4s r; r.v[0] = t.x; r.v[1] = t.y; r.v[2] = t.z; r.v[3] = t.w; return r;
}

// ---------------- pre-kernels ----------------

__global__ void k_base(const float* __restrict__ ctx,
                       const float* __restrict__ w1,
                       const float* __restrict__ b1,
                       float* __restrict__ base) {
    const int b = blockIdx.x, n = threadIdx.x;
    float acc = b1[n];
    for (int c = 0; c < 128; ++c)
        acc += ctx[b * 128 + c] * w1[(3 + c) * 256 + n];
    base[b * 256 + n] = acc;
}

// wf[((kk*4+q)*256+n)*8+j] = bf16(W[kk*32+q*8+j][n])
__global__ void k_frag(const float* __restrict__ w,
                       unsigned short* __restrict__ wf) {
    const int t = blockIdx.x * blockDim.x + threadIdx.x;  // 0..65535
    const int j = t & 7, n = (t >> 3) & 255, q = (t >> 11) & 3, kk = t >> 13;
    wf[t] = f2bf(w[(kk * 32 + q * 8 + j) * 256 + n]);
}

// ---------------- gemm: B-fragments direct from global (no staging barriers) ----------------
__device__ __forceinline__ void do_gemm_direct(const unsigned short* __restrict__ wf,
                                               const unsigned short* Asl,
                                               int raP, int vbB,
                                               f32x4 aP[8], f32x4 aT0[8], f32x4 aT1[8]) {
    const bf16x8* __restrict__ wp = (const bf16x8*)wf;
    const int base = vbB >> 3;           // bf16x8-unit index
    bf16x8 cur[8], nxt[8];
#pragma unroll
    for (int nb = 0; nb < 8; ++nb) cur[nb] = wp[base + nb * 16];
#pragma unroll 1
    for (int kk = 0; kk < 8; ++kk) {
        if (kk < 7) {
#pragma unroll
            for (int nb = 0; nb < 8; ++nb) nxt[nb] = wp[(kk + 1) * 1024 + base + nb * 16];
        }
        const bf16x8 fP  = *(const bf16x8*)(Asl + raP + kk * 32);
        const bf16x8 fT0 = *(const bf16x8*)(Asl + raP + T0OFF + kk * 32);
        const bf16x8 fT1 = *(const bf16x8*)(Asl + raP + T1OFF + kk * 32);
#pragma unroll
        for (int nb = 0; nb < 8; ++nb) {
            aP[nb]  = __builtin_amdgcn_mfma_f32_16x16x32_bf16(fP,  cur[nb], aP[nb],  0, 0, 0);
            aT0[nb] = __builtin_amdgcn_mfma_f32_16x16x32_bf16(fT0, cur[nb], aT0[nb], 0, 0, 0);
            aT1[nb] = __builtin_amdgcn_mfma_f32_16x16x32_bf16(fT1, cur[nb], aT1[nb], 0, 0, 0);
        }
#pragma unroll
        for (int nb = 0; nb < 8; ++nb) cur[nb] = nxt[nb];
    }
}

__device__ __forceinline__ void el_write(unsigned short* Asl,
                                         const f32x4* aP, const f32x4* aT0, const f32x4* aT1,
                                         const float* br, int wbE, int wbO) {
#pragma unroll
    for (int nb = 0; nb < 8; ++nb) {
        const int cbase = ((nb & 1) ? wbO : wbE) + (nb >> 1) * 32;
#pragma unroll
        for (int r = 0; r < 4; ++r) {
            const float pre = aP[nb][r] + br[nb];
            const float s = sigm(pre);
            const float h = pre * s;
            const float d = s + h - h * s;  // silu'(pre)
            Asl[cbase + r * AS]          = f2bf_fast(h);
            Asl[cbase + r * AS + T0OFF]  = f2bf_fast(d * aT0[nb][r]);
            Asl[cbase + r * AS + T1OFF]  = f2bf_fast(d * aT1[nb][r]);
        }
    }
}

// ---------------- main kernel ----------------
// One WG = 32 points of one batch, 256 threads (4 waves), 2 WGs/CU.
__launch_bounds__(256, 2)
__global__ void k_main(const float* __restrict__ x,
                       const float* __restrict__ w1,
                       const float* __restrict__ b2g,
                       const float* __restrict__ b3g,
                       const float* __restrict__ w4g,
                       const float* __restrict__ b4g,
                       const unsigned short* __restrict__ w2f,
                       const unsigned short* __restrict__ w3f,
                       const float* __restrict__ basep,
                       float* __restrict__ ldacc,
                       float* __restrict__ out) {
    __shared__ unsigned short Asl[96 * AS];    // [h;t0;t1] bf16, swizzled (32 rows each)
    __shared__ float w1r[3][256];
    __shared__ float basel[256];
    __shared__ float w40[256], w41[256];
    __shared__ float ptsl[32][2];
    __shared__ float ldl[32];
    __shared__ float b4l[2];

    const int tid = threadIdx.x;
    const int wg = blockIdx.x;
    const int b = wg >> 7;                // 128 WGs per batch
    const int n0 = (wg & 127) << 5;       // 32 points per WG

    for (int i = tid; i < 768; i += 256) w1r[i >> 8][i & 255] = w1[i];
    basel[tid] = basep[b * 256 + tid];
    w40[tid] = w4g[2 * tid]; w41[tid] = w4g[2 * tid + 1];
    if (tid < 64) ptsl[tid >> 1][tid & 1] = x[((b << 12) + n0 + (tid >> 1)) * 2 + (tid & 1)];
    if (tid < 32) ldl[tid] = 0.0f;
    if (tid < 2) b4l[tid] = b4g[tid];

    const int lane = tid & 63, wave = tid >> 6;
    const int m = lane & 15, q = lane >> 4;
    const int tw = wave & 1;                 // M-triple index (2 tiles of 16 points)
    const int nbb = (wave >> 1) << 3;        // N-block base (0 or 8)
    const int qx = q ^ ((m >> 2) & 3);       // read-side XOR swizzle
    const int raP = (tw * 16 + m) * AS + qx * 8;
    const int mw  = m ^ ((q & 1) << 3);      // write-side swizzle pieces
    const int nbx = q >> 1;
    const int wbE = (tw * 16 + q * 4) * AS + (nbb + nbx) * 16 + mw;
    const int wbO = (tw * 16 + q * 4) * AS + (nbb + (1 ^ nbx)) * 16 + mw;
    const int vbB = q * 2048 + (nbb * 16 + m) * 8;

    float b2r[8], b3r[8];
#pragma unroll
    for (int i = 0; i < 8; ++i) {
        b2r[i] = b2g[(nbb + i) * 16 + m];
        b3r[i] = b3g[(nbb + i) * 16 + m];
    }
    __syncthreads();

    const int p4 = tid >> 3;            // point (0..31) for L1/L4 phases
    const int ic = tid & 7;             // 8 threads per point
    const int px = (p4 & 12) << 1;      // col XOR for rows p4, 32+p4, 64+p4

#pragma unroll 1
    for (int st = 0; st < 10; ++st) {
        const float ti = 0.1f * (float)st;
        // ---------- layer 1 ----------
        {
            const float x0 = ptsl[p4][0], x1 = ptsl[p4][1];
#pragma unroll
            for (int g = 0; g < 8; ++g) {
                const int cb = (ic << 5) + g * 4;
                const f4s wa = ld4(&w1r[0][cb]);
                const f4s wb = ld4(&w1r[1][cb]);
                const f4s wc = ld4(&w1r[2][cb]);
                const f4s bs = ld4(&basel[cb]);
                float hf[4], t0f[4], t1f[4];
#pragma unroll
                for (int e = 0; e < 4; ++e) {
                    const float pre = x0 * wa.v[e] + x1 * wb.v[e] + ti * wc.v[e] + bs.v[e];
                    const float s = sigm(pre);
                    const float h = pre * s;
                    const float d = s + h - h * s;
                    hf[e]  = h;
                    t0f[e] = d * wa.v[e];
                    t1f[e] = d * wb.v[e];
                }
                const int colp = cb ^ px;
                uint2 v0, v1, v2;
                v0.x = pack2bf(hf[0],  hf[1]);  v0.y = pack2bf(hf[2],  hf[3]);
                v1.x = pack2bf(t0f[0], t0f[1]); v1.y = pack2bf(t0f[2], t0f[3]);
                v2.x = pack2bf(t1f[0], t1f[1]); v2.y = pack2bf(t1f[2], t1f[3]);
                *(uint2*)(Asl + p4 * AS + colp) = v0;
                *(uint2*)(Asl + T0OFF + p4 * AS + colp) = v1;
                *(uint2*)(Asl + T1OFF + p4 * AS + colp) = v2;
            }
        }
        __syncthreads();

        // ---------- layer 2 (barrier-free K-loop) ----------
        f32x4 aP[8], aT0[8], aT1[8];
#pragma unroll
        for (int i = 0; i < 8; ++i) { aP[i] = f32x4{0.f,0.f,0.f,0.f}; aT0[i] = f32x4{0.f,0.f,0.f,0.f}; aT1[i] = f32x4{0.f,0.f,0.f,0.f}; }
        do_gemm_direct(w2f, Asl, raP, vbB, aP, aT0, aT1);
        el_write(Asl, aP, aT0, aT1, b2r, wbE, wbO);
        __syncthreads();

        // ---------- layer 3 (barrier-free K-loop) ----------
#pragma unroll
        for (int i = 0; i < 8; ++i) { aP[i] = f32x4{0.f,0.f,0.f,0.f}; aT0[i] = f32x4{0.f,0.f,0.f,0.f}; aT1[i] = f32x4{0.f,0.f,0.f,0.f}; }
        do_gemm_direct(w3f, Asl, raP, vbB, aP, aT0, aT1);
        el_write(Asl, aP, aT0, aT1, b3r, wbE, wbO);
        __syncthreads();

        // ---------- layer 4 + update ----------
        {
            float v0 = 0.f, v1 = 0.f, j00 = 0.f, j11 = 0.f;
#pragma unroll
            for (int g = 0; g < 8; ++g) {
                const int cb = (ic << 5) + g * 4;
                const int colp = cb ^ px;
                const uint2 hv  = *(const uint2*)(Asl + p4 * AS + colp);
                const uint2 t0v = *(const uint2*)(Asl + T0OFF + p4 * AS + colp);
                const uint2 t1v = *(const uint2*)(Asl + T1OFF + p4 * AS + colp);
                const f4s wa = ld4(&w40[cb]);
                const f4s wb = ld4(&w41[cb]);
                const unsigned hu[4]  = { hv.x & 0xffffu,  hv.x >> 16,  hv.y & 0xffffu,  hv.y >> 16 };
                const unsigned t0u[4] = { t0v.x & 0xffffu, t0v.x >> 16, t0v.y & 0xffffu, t0v.y >> 16 };
                const unsigned t1u[4] = { t1v.x & 0xffffu, t1v.x >> 16, t1v.y & 0xffffu, t1v.y >> 16 };
#pragma unroll
                for (int e = 0; e < 4; ++e) {
                    const float h = bf2f(hu[e]);
                    v0  += h * wa.v[e];
                    v1  += h * wb.v[e];
                    j00 += bf2f(t0u[e]) * wa.v[e];
                    j11 += bf2f(t1u[e]) * wb.v[e];
                }
            }
#pragma unroll
            for (int o = 1; o < 8; o <<= 1) {
                v0  += __shfl_xor(v0, o);
                v1  += __shfl_xor(v1, o);
                j00 += __shfl_xor(j00, o);
                j11 += __shfl_xor(j11, o);
            }
            if (ic == 0) {
                ptsl[p4][0] += 0.1f * (v0 + b4l[0]);
                ptsl[p4][1] += 0.1f * (v1 + b4l[1]);
                ldl[p4]     += 0.1f * (j00 + j11);
            }
        }
        __syncthreads();
    }

    // ---------- epilogue: FP32 output ----------
    if (tid < 64) {
        const int p = tid >> 1, c = tid & 1;
        out[((b << 12) + n0 + p) * 2 + c] = ptsl[p][c];
    }
    if (wave == 0) {
        float v = (lane < 32) ? ldl[lane] : 0.0f;
#pragma unroll
        for (int o = 32; o > 0; o >>= 1) v += __shfl_xor(v, o);
        if (lane == 0) atomicAdd(ldacc + b, v);
    }
}

// copy 64 float accumulators -> fp32 logdet outputs
__global__ void k_fin(const float* __restrict__ ldacc, float* __restrict__ out) {
    out[524288 + threadIdx.x] = ldacc[threadIdx.x];
}

extern "C" void kernel_launch(void* const* d_in, const int* in_sizes, int n_in,
                              void* d_out, int out_size, void* d_ws, size_t ws_size,
                              hipStream_t stream) {
    const float* x   = (const float*)d_in[0];
    const float* ctx = (const float*)d_in[1];
    const float* w1  = (const float*)d_in[2];
    const float* b1  = (const float*)d_in[3];
    const float* w2  = (const float*)d_in[4];
    const float* b2  = (const float*)d_in[5];
    const float* w3  = (const float*)d_in[6];
    const float* b3  = (const float*)d_in[7];
    const float* w4  = (const float*)d_in[8];
    const float* b4  = (const float*)d_in[9];

    // d_ws layout: [0,128K) w2f bf16 | [128K,256K) w3f bf16 | [256K,320K) base fp32 | [320K,+256) ldacc
    char* ws = (char*)d_ws;
    unsigned short* w2f = (unsigned short*)ws;
    unsigned short* w3f = (unsigned short*)(ws + 131072);
    float* basep = (float*)(ws + 262144);
    float* ldacc = (float*)(ws + 327680);
    float* out = (float*)d_out;

    hipMemsetAsync(ldacc, 0, 64 * sizeof(float), stream);
    k_base<<<dim3(64), dim3(256), 0, stream>>>(ctx, w1, b1, basep);
    k_frag<<<dim3(128), dim3(512), 0, stream>>>(w2, w2f);
    k_frag<<<dim3(128), dim3(512), 0, stream>>>(w3, w3f);
    k_main<<<dim3(8192), dim3(256), 0, stream>>>(x, w1, b2, b3, w4, b4, w2f, w3f, basep, ldacc, out);
    k_fin<<<dim3(1), dim3(64), 0, stream>>>(ldacc, out);
}

// Round 14
// 2796.373 us; speedup vs baseline: 1.9864x; 1.1767x over previous
//
#include <hip/hip_runtime.h>

typedef short bf16x8 __attribute__((ext_vector_type(8)));
typedef float f32x4 __attribute__((ext_vector_type(4)));

#define AS 272            // A-matrix LDS row stride in bf16 elements
#define T0OFF (32 * AS)   // tangent-0 row block offset (32 points/WG)
#define T1OFF (64 * AS)   // tangent-1 row block offset

__device__ __forceinline__ unsigned short f2bf(float f) {      // RNE (pre-kernels only)
    union { float f; unsigned int u; } v; v.f = f;
    unsigned int u = v.u + 0x7FFFu + ((v.u >> 16) & 1u);
    return (unsigned short)(u >> 16);
}
__device__ __forceinline__ unsigned short f2bf_fast(float f) { // round-half-up, 2 ops
    union { float f; unsigned int u; } v; v.f = f;
    return (unsigned short)((v.u + 0x8000u) >> 16);
}
__device__ __forceinline__ unsigned pack2bf(float a, float b) { // [lo=a, hi=b]
    union { float f; unsigned u; } x, y; x.f = a; y.f = b;
    return ((x.u + 0x8000u) >> 16) | ((y.u + 0x8000u) & 0xffff0000u);
}
__device__ __forceinline__ float bf2f(unsigned int h) {
    union { unsigned int u; float f; } v; v.u = h << 16; return v.f;
}
__device__ __forceinline__ float sigm(float x) {
    return __builtin_amdgcn_rcpf(1.0f + __expf(-x));
}

struct f4s { float v[4]; };
__device__ __forceinline__ f4s ld4(const float* p) {
    float4 t = *(const float4*)p;
    f4s r; r.v[0] = t.x; r.v[1] = t.y; r.v[2] = t.z; r.v[3] = t.w; return r;
}

// ---------------- pre-kernels ----------------

__global__ void k_base(const float* __restrict__ ctx,
                       const float* __restrict__ w1,
                       const float* __restrict__ b1,
                       float* __restrict__ base) {
    const int b = blockIdx.x, n = threadIdx.x;
    float acc = b1[n];
    for (int c = 0; c < 128; ++c)
        acc += ctx[b * 128 + c] * w1[(3 + c) * 256 + n];
    base[b * 256 + n] = acc;
}

// wf[((kk*4+q)*256+n)*8+j] = bf16(W[kk*32+q*8+j][n])
__global__ void k_frag(const float* __restrict__ w,
                       unsigned short* __restrict__ wf) {
    const int t = blockIdx.x * blockDim.x + threadIdx.x;  // 0..65535
    const int j = t & 7, n = (t >> 3) & 255, q = (t >> 11) & 3, kk = t >> 13;
    wf[t] = f2bf(w[(kk * 32 + q * 8 + j) * 256 + n]);
}

// ---------------- gemm: direct global B-fragments, K-unroll-2 ping-pong ----------------
#define MFMA3(frag_base, buf)                                                              \
    {                                                                                      \
        const bf16x8 fP  = *(const bf16x8*)(Asl + (frag_base));                            \
        const bf16x8 fT0 = *(const bf16x8*)(Asl + (frag_base) + T0OFF);                    \
        const bf16x8 fT1 = *(const bf16x8*)(Asl + (frag_base) + T1OFF);                    \
        _Pragma("unroll")                                                                  \
        for (int nb = 0; nb < 8; ++nb) {                                                   \
            aP[nb]  = __builtin_amdgcn_mfma_f32_16x16x32_bf16(fP,  buf[nb], aP[nb],  0, 0, 0); \
            aT0[nb] = __builtin_amdgcn_mfma_f32_16x16x32_bf16(fT0, buf[nb], aT0[nb], 0, 0, 0); \
            aT1[nb] = __builtin_amdgcn_mfma_f32_16x16x32_bf16(fT1, buf[nb], aT1[nb], 0, 0, 0); \
        }                                                                                  \
    }

__device__ __forceinline__ void do_gemm_direct(const unsigned short* __restrict__ wf,
                                               const unsigned short* Asl,
                                               int raP, int vbB,
                                               f32x4 aP[8], f32x4 aT0[8], f32x4 aT1[8]) {
    const bf16x8* __restrict__ wp = (const bf16x8*)wf;
    const int base = vbB >> 3;           // bf16x8-unit index
    bf16x8 bufA[8], bufB[8];
#pragma unroll
    for (int nb = 0; nb < 8; ++nb) bufA[nb] = wp[base + nb * 16];
#pragma unroll 1
    for (int kk = 0; kk < 8; kk += 2) {
#pragma unroll
        for (int nb = 0; nb < 8; ++nb) bufB[nb] = wp[(kk + 1) * 1024 + base + nb * 16];
        MFMA3(raP + kk * 32, bufA);
        if (kk + 2 < 8) {
#pragma unroll
            for (int nb = 0; nb < 8; ++nb) bufA[nb] = wp[(kk + 2) * 1024 + base + nb * 16];
        }
        MFMA3(raP + (kk + 1) * 32, bufB);
    }
}

__device__ __forceinline__ void el_write(unsigned short* Asl,
                                         const f32x4* aP, const f32x4* aT0, const f32x4* aT1,
                                         const float* br, int wbE, int wbO) {
#pragma unroll
    for (int nb = 0; nb < 8; ++nb) {
        const int cbase = ((nb & 1) ? wbO : wbE) + (nb >> 1) * 32;
#pragma unroll
        for (int r = 0; r < 4; ++r) {
            const float pre = aP[nb][r] + br[nb];
            const float s = sigm(pre);
            const float h = pre * s;
            const float d = fmaf(h, 1.0f - s, s);  // silu'(pre)
            Asl[cbase + r * AS]          = f2bf_fast(h);
            Asl[cbase + r * AS + T0OFF]  = f2bf_fast(d * aT0[nb][r]);
            Asl[cbase + r * AS + T1OFF]  = f2bf_fast(d * aT1[nb][r]);
        }
    }
}

// ---------------- main kernel ----------------
// One WG = 32 points of one batch, 256 threads (4 waves), 2 WGs/CU.
// Points live in registers; L4 and next-step L1 are fused (3 barriers/step).
__launch_bounds__(256, 2)
__global__ void k_main(const float* __restrict__ x,
                       const float* __restrict__ w1,
                       const float* __restrict__ b2g,
                       const float* __restrict__ b3g,
                       const float* __restrict__ w4g,
                       const float* __restrict__ b4g,
                       const unsigned short* __restrict__ w2f,
                       const unsigned short* __restrict__ w3f,
                       const float* __restrict__ basep,
                       float* __restrict__ ldacc,
                       float* __restrict__ out) {
    __shared__ unsigned short Asl[96 * AS];    // [h;t0;t1] bf16, swizzled (32 rows each)
    __shared__ float w1r[3][256];
    __shared__ float basel[256];
    __shared__ float w40[256], w41[256];
    __shared__ float ldl[32];
    __shared__ float b4l[2];

    const int tid = threadIdx.x;
    const int wg = blockIdx.x;
    const int b = wg >> 7;                // 128 WGs per batch
    const int n0 = (wg & 127) << 5;       // 32 points per WG

    for (int i = tid; i < 768; i += 256) w1r[i >> 8][i & 255] = w1[i];
    basel[tid] = basep[b * 256 + tid];
    w40[tid] = w4g[2 * tid]; w41[tid] = w4g[2 * tid + 1];
    if (tid < 2) b4l[tid] = b4g[tid];

    const int lane = tid & 63, wave = tid >> 6;
    const int m = lane & 15, q = lane >> 4;
    const int tw = wave & 1;                 // M-triple index (2 tiles of 16 points)
    const int nbb = (wave >> 1) << 3;        // N-block base (0 or 8)
    const int qx = q ^ ((m >> 2) & 3);       // read-side XOR swizzle
    const int raP = (tw * 16 + m) * AS + qx * 8;
    const int mw  = m ^ ((q & 1) << 3);      // write-side swizzle pieces
    const int nbx = q >> 1;
    const int wbE = (tw * 16 + q * 4) * AS + (nbb + nbx) * 16 + mw;
    const int wbO = (tw * 16 + q * 4) * AS + (nbb + (1 ^ nbx)) * 16 + mw;
    const int vbB = q * 2048 + (nbb * 16 + m) * 8;

    float b2r[8], b3r[8];
#pragma unroll
    for (int i = 0; i < 8; ++i) {
        b2r[i] = b2g[(nbb + i) * 16 + m];
        b3r[i] = b3g[(nbb + i) * 16 + m];
    }

    const int p4 = tid >> 3;            // point (0..31) for L1/L4 phases
    const int ic = tid & 7;             // 8 threads per point
    const int px = (p4 & 12) << 1;      // col XOR for rows p4, 32+p4, 64+p4

    // register-resident point state (replicated across the point's 8 lanes)
    float x0 = x[((b << 12) + n0 + p4) * 2];
    float x1 = x[((b << 12) + n0 + p4) * 2 + 1];
    float ldreg = 0.0f;
    const float b40 = b4g[0], b41 = b4g[1];
    __syncthreads();

#pragma unroll 1
    for (int st = 0; st < 10; ++st) {
        const float ti = 0.1f * (float)st;
        // ---------- layer 1 (fused with previous step's L4; registers only) ----------
#pragma unroll
        for (int g = 0; g < 8; ++g) {
            const int cb = (ic << 5) + g * 4;
            const f4s wa = ld4(&w1r[0][cb]);
            const f4s wb = ld4(&w1r[1][cb]);
            const f4s wc = ld4(&w1r[2][cb]);
            const f4s bs = ld4(&basel[cb]);
            float hf[4], t0f[4], t1f[4];
#pragma unroll
            for (int e = 0; e < 4; ++e) {
                const float pre = x0 * wa.v[e] + x1 * wb.v[e] + ti * wc.v[e] + bs.v[e];
                const float s = sigm(pre);
                const float h = pre * s;
                const float d = fmaf(h, 1.0f - s, s);
                hf[e]  = h;
                t0f[e] = d * wa.v[e];
                t1f[e] = d * wb.v[e];
            }
            const int colp = cb ^ px;
            uint2 v0, v1, v2;
            v0.x = pack2bf(hf[0],  hf[1]);  v0.y = pack2bf(hf[2],  hf[3]);
            v1.x = pack2bf(t0f[0], t0f[1]); v1.y = pack2bf(t0f[2], t0f[3]);
            v2.x = pack2bf(t1f[0], t1f[1]); v2.y = pack2bf(t1f[2], t1f[3]);
            *(uint2*)(Asl + p4 * AS + colp) = v0;
            *(uint2*)(Asl + T0OFF + p4 * AS + colp) = v1;
            *(uint2*)(Asl + T1OFF + p4 * AS + colp) = v2;
        }
        __syncthreads();

        // ---------- layer 2 (barrier-free K-loop) ----------
        f32x4 aP[8], aT0[8], aT1[8];
#pragma unroll
        for (int i = 0; i < 8; ++i) { aP[i] = f32x4{0.f,0.f,0.f,0.f}; aT0[i] = f32x4{0.f,0.f,0.f,0.f}; aT1[i] = f32x4{0.f,0.f,0.f,0.f}; }
        do_gemm_direct(w2f, Asl, raP, vbB, aP, aT0, aT1);
        el_write(Asl, aP, aT0, aT1, b2r, wbE, wbO);
        __syncthreads();

        // ---------- layer 3 (barrier-free K-loop) ----------
#pragma unroll
        for (int i = 0; i < 8; ++i) { aP[i] = f32x4{0.f,0.f,0.f,0.f}; aT0[i] = f32x4{0.f,0.f,0.f,0.f}; aT1[i] = f32x4{0.f,0.f,0.f,0.f}; }
        do_gemm_direct(w3f, Asl, raP, vbB, aP, aT0, aT1);
        el_write(Asl, aP, aT0, aT1, b3r, wbE, wbO);
        __syncthreads();

        // ---------- layer 4 + point update (registers; no trailing barrier) ----------
        {
            float v0 = 0.f, v1 = 0.f, j00 = 0.f, j11 = 0.f;
#pragma unroll
            for (int g = 0; g < 8; ++g) {
                const int cb = (ic << 5) + g * 4;
                const int colp = cb ^ px;
                const uint2 hv  = *(const uint2*)(Asl + p4 * AS + colp);
                const uint2 t0v = *(const uint2*)(Asl + T0OFF + p4 * AS + colp);
                const uint2 t1v = *(const uint2*)(Asl + T1OFF + p4 * AS + colp);
                const f4s wa = ld4(&w40[cb]);
                const f4s wb = ld4(&w41[cb]);
                const unsigned hu[4]  = { hv.x & 0xffffu,  hv.x >> 16,  hv.y & 0xffffu,  hv.y >> 16 };
                const unsigned t0u[4] = { t0v.x & 0xffffu, t0v.x >> 16, t0v.y & 0xffffu, t0v.y >> 16 };
                const unsigned t1u[4] = { t1v.x & 0xffffu, t1v.x >> 16, t1v.y & 0xffffu, t1v.y >> 16 };
#pragma unroll
                for (int e = 0; e < 4; ++e) {
                    const float h = bf2f(hu[e]);
                    v0  += h * wa.v[e];
                    v1  += h * wb.v[e];
                    j00 += bf2f(t0u[e]) * wa.v[e];
                    j11 += bf2f(t1u[e]) * wb.v[e];
                }
            }
#pragma unroll
            for (int o = 1; o < 8; o <<= 1) {    // butterfly: identical sums in all 8 lanes
                v0  += __shfl_xor(v0, o);
                v1  += __shfl_xor(v1, o);
                j00 += __shfl_xor(j00, o);
                j11 += __shfl_xor(j11, o);
            }
            x0 += 0.1f * (v0 + b40);
            x1 += 0.1f * (v1 + b41);
            ldreg += 0.1f * (j00 + j11);
            // WAR on Asl is same-thread/same-address (next L1 writes what this L4 read):
            // no barrier needed before the next iteration's L1.
        }
    }

    // ---------- epilogue: FP32 output ----------
    if (ic == 0) {
        out[((b << 12) + n0 + p4) * 2]     = x0;
        out[((b << 12) + n0 + p4) * 2 + 1] = x1;
        ldl[p4] = ldreg;
    }
    __syncthreads();
    if (wave == 0) {
        float v = (lane < 32) ? ldl[lane] : 0.0f;
#pragma unroll
        for (int o = 32; o > 0; o >>= 1) v += __shfl_xor(v, o);
        if (lane == 0) atomicAdd(ldacc + b, v);
    }
}

// copy 64 float accumulators -> fp32 logdet outputs
__global__ void k_fin(const float* __restrict__ ldacc, float* __restrict__ out) {
    out[524288 + threadIdx.x] = ldacc[threadIdx.x];
}

extern "C" void kernel_launch(void* const* d_in, const int* in_sizes, int n_in,
                              void* d_out, int out_size, void* d_ws, size_t ws_size,
                              hipStream_t stream) {
    const float* x   = (const float*)d_in[0];
    const float* ctx = (const float*)d_in[1];
    const float* w1  = (const float*)d_in[2];
    const float* b1  = (const float*)d_in[3];
    const float* w2  = (const float*)d_in[4];
    const float* b2  = (const float*)d_in[5];
    const float* w3  = (const float*)d_in[6];
    const float* b3  = (const float*)d_in[7];
    const float* w4  = (const float*)d_in[8];
    const float* b4  = (const float*)d_in[9];

    // d_ws layout: [0,128K) w2f bf16 | [128K,256K) w3f bf16 | [256K,320K) base fp32 | [320K,+256) ldacc
    char* ws = (char*)d_ws;
    unsigned short* w2f = (unsigned short*)ws;
    unsigned short* w3f = (unsigned short*)(ws + 131072);
    float* basep = (float*)(ws + 262144);
    float* ldacc = (float*)(ws + 327680);
    float* out = (float*)d_out;

    hipMemsetAsync(ldacc, 0, 64 * sizeof(float), stream);
    k_base<<<dim3(64), dim3(256), 0, stream>>>(ctx, w1, b1, basep);
    k_frag<<<dim3(128), dim3(512), 0, stream>>>(w2, w2f);
    k_frag<<<dim3(128), dim3(512), 0, stream>>>(w3, w3f);
    k_main<<<dim3(8192), dim3(256), 0, stream>>>(x, w1, b2, b3, w4, b4, w2f, w3f, basep, ldacc, out);
    k_fin<<<dim3(1), dim3(64), 0, stream>>>(ldacc, out);
}

// Round 15
// 2735.465 us; speedup vs baseline: 2.0307x; 1.0223x over previous
//
#include <hip/hip_runtime.h>

typedef short bf16x8 __attribute__((ext_vector_type(8)));
typedef float f32x4 __attribute__((ext_vector_type(4)));

#define AS 264            // plain layout; 528B row stride => <=2-way LDS aliasing (free)
#define T0OFF (32 * AS)
#define T1OFF (64 * AS)

__device__ __forceinline__ unsigned short f2bf(float f) {      // RNE (pre-kernels only)
    union { float f; unsigned int u; } v; v.f = f;
    unsigned int u = v.u + 0x7FFFu + ((v.u >> 16) & 1u);
    return (unsigned short)(u >> 16);
}
__device__ __forceinline__ unsigned short f2bf_fast(float f) { // round-half-up, 2 ops
    union { float f; unsigned int u; } v; v.f = f;
    return (unsigned short)((v.u + 0x8000u) >> 16);
}
__device__ __forceinline__ unsigned pack2bf(float a, float b) { // [lo=a, hi=b]
    union { float f; unsigned u; } x, y; x.f = a; y.f = b;
    return ((x.u + 0x8000u) >> 16) | ((y.u + 0x8000u) & 0xffff0000u);
}
__device__ __forceinline__ float bf2f(unsigned int h) {
    union { unsigned int u; float f; } v; v.u = h << 16; return v.f;
}
__device__ __forceinline__ float sigm(float x) {
    return __builtin_amdgcn_rcpf(1.0f + __expf(-x));
}

struct f4s { float v[4]; };
__device__ __forceinline__ f4s ld4(const float* p) {
    float4 t = *(const float4*)p;
    f4s r; r.v[0] = t.x; r.v[1] = t.y; r.v[2] = t.z; r.v[3] = t.w; return r;
}

// ---------------- pre-kernels ----------------

__global__ void k_base(const float* __restrict__ ctx,
                       const float* __restrict__ w1,
                       const float* __restrict__ b1,
                       float* __restrict__ base) {
    const int b = blockIdx.x, n = threadIdx.x;
    float acc = b1[n];
    for (int c = 0; c < 128; ++c)
        acc += ctx[b * 128 + c] * w1[(3 + c) * 256 + n];
    base[b * 256 + n] = acc;
}

// wf[((kk*4+q)*256+n)*8+j] = bf16(W[kk*32+q*8+j][n])
__global__ void k_frag(const float* __restrict__ w,
                       unsigned short* __restrict__ wf) {
    const int t = blockIdx.x * blockDim.x + threadIdx.x;  // 0..65535
    const int j = t & 7, n = (t >> 3) & 255, q = (t >> 11) & 3, kk = t >> 13;
    wf[t] = f2bf(w[(kk * 32 + q * 8 + j) * 256 + n]);
}

// ---------------- gemm: direct global B-fragments, 4 nb per wave, ping-pong ----------------
#define MFMA3(frag_base, buf)                                                              \
    {                                                                                      \
        const bf16x8 fP  = *(const bf16x8*)(Asl + (frag_base));                            \
        const bf16x8 fT0 = *(const bf16x8*)(Asl + (frag_base) + T0OFF);                    \
        const bf16x8 fT1 = *(const bf16x8*)(Asl + (frag_base) + T1OFF);                    \
        _Pragma("unroll")                                                                  \
        for (int nb = 0; nb < 4; ++nb) {                                                   \
            aP[nb]  = __builtin_amdgcn_mfma_f32_16x16x32_bf16(fP,  buf[nb], aP[nb],  0, 0, 0); \
            aT0[nb] = __builtin_amdgcn_mfma_f32_16x16x32_bf16(fT0, buf[nb], aT0[nb], 0, 0, 0); \
            aT1[nb] = __builtin_amdgcn_mfma_f32_16x16x32_bf16(fT1, buf[nb], aT1[nb], 0, 0, 0); \
        }                                                                                  \
    }

__device__ __forceinline__ void do_gemm_direct(const unsigned short* __restrict__ wf,
                                               const unsigned short* Asl,
                                               int raP, int base0,
                                               f32x4 aP[4], f32x4 aT0[4], f32x4 aT1[4]) {
    const bf16x8* __restrict__ wp = (const bf16x8*)wf;
    bf16x8 bufA[4], bufB[4];
#pragma unroll
    for (int nb = 0; nb < 4; ++nb) bufA[nb] = wp[base0 + nb * 16];
#pragma unroll 1
    for (int kk = 0; kk < 8; kk += 2) {
#pragma unroll
        for (int nb = 0; nb < 4; ++nb) bufB[nb] = wp[(kk + 1) * 1024 + base0 + nb * 16];
        MFMA3(raP + kk * 32, bufA);
        if (kk + 2 < 8) {
#pragma unroll
            for (int nb = 0; nb < 4; ++nb) bufA[nb] = wp[(kk + 2) * 1024 + base0 + nb * 16];
        }
        MFMA3(raP + (kk + 1) * 32, bufB);
    }
}

// plain-layout epilogue: value (row,col) at Asl[row*AS+col]; acc pre-seeded with bias
__device__ __forceinline__ void el_write(unsigned short* Asl,
                                         const f32x4* aP, const f32x4* aT0, const f32x4* aT1,
                                         int ebase) {
#pragma unroll
    for (int nb = 0; nb < 4; ++nb) {
#pragma unroll
        for (int r = 0; r < 4; ++r) {
            const int a = ebase + nb * 16 + r * AS;
            const float pre = aP[nb][r];            // bias already in acc
            const float s = sigm(pre);
            const float h = pre * s;
            const float d = fmaf(h, 1.0f - s, s);   // silu'(pre)
            Asl[a]          = f2bf_fast(h);
            Asl[a + T0OFF]  = f2bf_fast(d * aT0[nb][r]);
            Asl[a + T1OFF]  = f2bf_fast(d * aT1[nb][r]);
        }
    }
}

// ---------------- main kernel ----------------
// One WG = 32 points, 512 threads (8 waves), 2 WGs/CU -> 16 waves/CU.
// Waves: tw=wave&1 (M-tile), nbb=(wave>>1)*4 (4 N-blocks). Plain Asl, no swizzle.
__launch_bounds__(512, 4)
__global__ void k_main(const float* __restrict__ x,
                       const float* __restrict__ w1,
                       const float* __restrict__ b2g,
                       const float* __restrict__ b3g,
                       const float* __restrict__ w4g,
                       const float* __restrict__ b4g,
                       const unsigned short* __restrict__ w2f,
                       const unsigned short* __restrict__ w3f,
                       const float* __restrict__ basep,
                       float* __restrict__ ldacc,
                       float* __restrict__ out) {
    __shared__ unsigned short Asl[96 * AS];    // [h;t0;t1] bf16, plain (32 rows each)
    __shared__ float w1r[3][256];
    __shared__ float basel[256];
    __shared__ float w40[256], w41[256];
    __shared__ float ldl[32];

    const int tid = threadIdx.x;
    const int wg = blockIdx.x;
    const int b = wg >> 7;                // 128 WGs per batch
    const int n0 = (wg & 127) << 5;       // 32 points per WG

    for (int i = tid; i < 768; i += 512) w1r[i >> 8][i & 255] = w1[i];
    if (tid < 256) basel[tid] = basep[b * 256 + tid];
    if (tid < 256) { w40[tid] = w4g[2 * tid]; w41[tid] = w4g[2 * tid + 1]; }

    const int lane = tid & 63, wave = tid >> 6;
    const int m = lane & 15, q = lane >> 4;
    const int tw = wave & 1;                 // M-tile (16 points)
    const int nbb = (wave >> 1) << 2;        // N-block base: 0,4,8,12
    const int raP   = (tw * 16 + m) * AS;    // A-frag row base (add kk*32 + q*8)
    const int raPq  = raP + q * 8;
    const int ebase = (tw * 16 + q * 4) * AS + nbb * 16 + m;   // el_write base
    const int base0 = q * 256 + nbb * 16 + m;                  // B-frag bf16x8-unit base

    float b2r[4], b3r[4];
#pragma unroll
    for (int i = 0; i < 4; ++i) {
        b2r[i] = b2g[(nbb + i) * 16 + m];
        b3r[i] = b3g[(nbb + i) * 16 + m];
    }

    const int p4 = tid >> 4;            // point (0..31)
    const int ic = tid & 15;            // 16 threads per point

    // register-resident point state (replicated across the point's 16 lanes)
    float x0 = x[((b << 12) + n0 + p4) * 2];
    float x1 = x[((b << 12) + n0 + p4) * 2 + 1];
    float ldreg = 0.0f;
    const float b40 = b4g[0], b41 = b4g[1];
    __syncthreads();

#pragma unroll 1
    for (int st = 0; st < 10; ++st) {
        const float ti = 0.1f * (float)st;
        // ---------- layer 1 (fused with previous step's L4; registers only) ----------
#pragma unroll
        for (int g = 0; g < 4; ++g) {
            const int cb = (ic << 4) + g * 4;
            const f4s wa = ld4(&w1r[0][cb]);
            const f4s wb = ld4(&w1r[1][cb]);
            const f4s wc = ld4(&w1r[2][cb]);
            const f4s bs = ld4(&basel[cb]);
            float hf[4], t0f[4], t1f[4];
#pragma unroll
            for (int e = 0; e < 4; ++e) {
                const float pre = x0 * wa.v[e] + x1 * wb.v[e] + ti * wc.v[e] + bs.v[e];
                const float s = sigm(pre);
                const float h = pre * s;
                const float d = fmaf(h, 1.0f - s, s);
                hf[e]  = h;
                t0f[e] = d * wa.v[e];
                t1f[e] = d * wb.v[e];
            }
            uint2 v0, v1, v2;
            v0.x = pack2bf(hf[0],  hf[1]);  v0.y = pack2bf(hf[2],  hf[3]);
            v1.x = pack2bf(t0f[0], t0f[1]); v1.y = pack2bf(t0f[2], t0f[3]);
            v2.x = pack2bf(t1f[0], t1f[1]); v2.y = pack2bf(t1f[2], t1f[3]);
            *(uint2*)(Asl + p4 * AS + cb) = v0;
            *(uint2*)(Asl + T0OFF + p4 * AS + cb) = v1;
            *(uint2*)(Asl + T1OFF + p4 * AS + cb) = v2;
        }
        __syncthreads();

        // ---------- layer 2 ----------
        f32x4 aP[4], aT0[4], aT1[4];
#pragma unroll
        for (int i = 0; i < 4; ++i) {
            aP[i]  = f32x4{b2r[i], b2r[i], b2r[i], b2r[i]};   // bias-seeded
            aT0[i] = f32x4{0.f, 0.f, 0.f, 0.f};
            aT1[i] = f32x4{0.f, 0.f, 0.f, 0.f};
        }
        do_gemm_direct(w2f, Asl, raPq, base0, aP, aT0, aT1);
        el_write(Asl, aP, aT0, aT1, ebase);
        __syncthreads();

        // ---------- layer 3 ----------
#pragma unroll
        for (int i = 0; i < 4; ++i) {
            aP[i]  = f32x4{b3r[i], b3r[i], b3r[i], b3r[i]};
            aT0[i] = f32x4{0.f, 0.f, 0.f, 0.f};
            aT1[i] = f32x4{0.f, 0.f, 0.f, 0.f};
        }
        do_gemm_direct(w3f, Asl, raPq, base0, aP, aT0, aT1);
        el_write(Asl, aP, aT0, aT1, ebase);
        __syncthreads();

        // ---------- layer 4 + point update (registers; no trailing barrier) ----------
        {
            float v0 = 0.f, v1 = 0.f, j00 = 0.f, j11 = 0.f;
#pragma unroll
            for (int g = 0; g < 4; ++g) {
                const int cb = (ic << 4) + g * 4;
                const uint2 hv  = *(const uint2*)(Asl + p4 * AS + cb);
                const uint2 t0v = *(const uint2*)(Asl + T0OFF + p4 * AS + cb);
                const uint2 t1v = *(const uint2*)(Asl + T1OFF + p4 * AS + cb);
                const f4s wa = ld4(&w40[cb]);
                const f4s wb = ld4(&w41[cb]);
                const unsigned hu[4]  = { hv.x & 0xffffu,  hv.x >> 16,  hv.y & 0xffffu,  hv.y >> 16 };
                const unsigned t0u[4] = { t0v.x & 0xffffu, t0v.x >> 16, t0v.y & 0xffffu, t0v.y >> 16 };
                const unsigned t1u[4] = { t1v.x & 0xffffu, t1v.x >> 16, t1v.y & 0xffffu, t1v.y >> 16 };
#pragma unroll
                for (int e = 0; e < 4; ++e) {
                    const float h = bf2f(hu[e]);
                    v0  += h * wa.v[e];
                    v1  += h * wb.v[e];
                    j00 += bf2f(t0u[e]) * wa.v[e];
                    j11 += bf2f(t1u[e]) * wb.v[e];
                }
            }
#pragma unroll
            for (int o = 1; o < 16; o <<= 1) {   // butterfly across the point's 16 lanes
                v0  += __shfl_xor(v0, o);
                v1  += __shfl_xor(v1, o);
                j00 += __shfl_xor(j00, o);
                j11 += __shfl_xor(j11, o);
            }
            x0 += 0.1f * (v0 + b40);
            x1 += 0.1f * (v1 + b41);
            ldreg += 0.1f * (j00 + j11);
            // next L1 writes the same Asl addresses this thread just read: no barrier.
        }
    }

    // ---------- epilogue: FP32 output ----------
    if (ic == 0) {
        out[((b << 12) + n0 + p4) * 2]     = x0;
        out[((b << 12) + n0 + p4) * 2 + 1] = x1;
        ldl[p4] = ldreg;
    }
    __syncthreads();
    if (wave == 0) {
        float v = (lane < 32) ? ldl[lane] : 0.0f;
#pragma unroll
        for (int o = 32; o > 0; o >>= 1) v += __shfl_xor(v, o);
        if (lane == 0) atomicAdd(ldacc + b, v);
    }
}

// copy 64 float accumulators -> fp32 logdet outputs
__global__ void k_fin(const float* __restrict__ ldacc, float* __restrict__ out) {
    out[524288 + threadIdx.x] = ldacc[threadIdx.x];
}

extern "C" void kernel_launch(void* const* d_in, const int* in_sizes, int n_in,
                              void* d_out, int out_size, void* d_ws, size_t ws_size,
                              hipStream_t stream) {
    const float* x   = (const float*)d_in[0];
    const float* ctx = (const float*)d_in[1];
    const float* w1  = (const float*)d_in[2];
    const float* b1  = (const float*)d_in[3];
    const float* w2  = (const float*)d_in[4];
    const float* b2  = (const float*)d_in[5];
    const float* w3  = (const float*)d_in[6];
    const float* b3  = (const float*)d_in[7];
    const float* w4  = (const float*)d_in[8];
    const float* b4  = (const float*)d_in[9];

    // d_ws layout: [0,128K) w2f bf16 | [128K,256K) w3f bf16 | [256K,320K) base fp32 | [320K,+256) ldacc
    char* ws = (char*)d_ws;
    unsigned short* w2f = (unsigned short*)ws;
    unsigned short* w3f = (unsigned short*)(ws + 131072);
    float* basep = (float*)(ws + 262144);
    float* ldacc = (float*)(ws + 327680);
    float* out = (float*)d_out;

    hipMemsetAsync(ldacc, 0, 64 * sizeof(float), stream);
    k_base<<<dim3(64), dim3(256), 0, stream>>>(ctx, w1, b1, basep);
    k_frag<<<dim3(128), dim3(512), 0, stream>>>(w2, w2f);
    k_frag<<<dim3(128), dim3(512), 0, stream>>>(w3, w3f);
    k_main<<<dim3(8192), dim3(512), 0, stream>>>(x, w1, b2, b3, w4, b4, w2f, w3f, basep, ldacc, out);
    k_fin<<<dim3(1), dim3(64), 0, stream>>>(ldacc, out);
}